// Round 3
// baseline (599.985 us; speedup 1.0000x reference)
//
#include <hip/hip_runtime.h>
#include <math.h>
#include <stdint.h>

// AttentionMC on MI355X: x(2,2048,1024) fp32; Wq/Wk/Wv/Wo(1024,1024) fp32.
// Split-bf16 (hi/lo, 3-term) MFMA implementation: ~1e-5 relative accuracy.
// Pipeline: split_convert -> qkv_mfma(+RoPE epilogue) -> vtrans -> attn_mfma -> proj_mfma.
// ws layout (96 MB): xhi xlo | whi wlo | qhi qlo khi klo vhi vlo | vthi vtlo
//   (xhi/xlo region is reused as ohi/olo after qkv consumes x).

#define S_LEN 2048
#define NHEAD 16
#define HDIM  64
#define NBH   32

typedef __attribute__((ext_vector_type(8))) short  bf16x8;
typedef __attribute__((ext_vector_type(4))) float  f32x4;
typedef unsigned short u16;
typedef unsigned int   u32;

__device__ __forceinline__ u16 f2bf(float f) {          // RNE fp32->bf16 bits
    u32 u = __float_as_uint(f);
    return (u16)((u + 0x7FFFu + ((u >> 16) & 1u)) >> 16);
}
__device__ __forceinline__ float bf2f(u16 s) {
    return __uint_as_float(((u32)s) << 16);
}
__device__ __forceinline__ f32x4 mfma16(bf16x8 a, bf16x8 b, f32x4 c) {
    return __builtin_amdgcn_mfma_f32_16x16x32_bf16(a, b, c, 0, 0, 0);
}
__device__ __forceinline__ void gll16(const void* g, void* l) {
    __builtin_amdgcn_global_load_lds((const __attribute__((address_space(1))) u32*)g,
                                     (__attribute__((address_space(3))) u32*)l, 16, 0, 0);
}

// ---------------- 1. fp32 -> bf16 hi/lo split for x and all weights ----------------
__global__ __launch_bounds__(256)
void split_convert(const float* __restrict__ x,
                   const float* __restrict__ Wq, const float* __restrict__ Wk,
                   const float* __restrict__ Wv, const float* __restrict__ Wo,
                   u16* __restrict__ xhi, u16* __restrict__ xlo,
                   u16* __restrict__ whi, u16* __restrict__ wlo)
{
    const int g = blockIdx.x * 256 + threadIdx.x;   // float4 index, 2M total
    const float* src; u16 *dhi, *dlo; int loc;
    if (g < 1048576) { src = x; dhi = xhi; dlo = xlo; loc = g; }
    else {
        const int r = g - 1048576;
        const int wsel = r >> 18;                   // 256K float4 per weight
        loc = r & 262143;
        src = (wsel == 0) ? Wq : (wsel == 1) ? Wk : (wsel == 2) ? Wv : Wo;
        dhi = whi + ((size_t)wsel << 20);
        dlo = wlo + ((size_t)wsel << 20);
    }
    const float4 v = reinterpret_cast<const float4*>(src)[loc];
    ushort4 hv, lv;
    hv.x = f2bf(v.x); lv.x = f2bf(v.x - bf2f(hv.x));
    hv.y = f2bf(v.y); lv.y = f2bf(v.y - bf2f(hv.y));
    hv.z = f2bf(v.z); lv.z = f2bf(v.z - bf2f(hv.z));
    hv.w = f2bf(v.w); lv.w = f2bf(v.w - bf2f(hv.w));
    reinterpret_cast<ushort4*>(dhi)[loc] = hv;
    reinterpret_cast<ushort4*>(dlo)[loc] = lv;
}

// ---------------- 2. QKV projection GEMM (hi/lo MFMA) + RoPE epilogue ----------------
// M=4096, Nglobal=3072 (q|k|v), K=1024. 128x128 tile, BK=32, 4 waves (64x64 each).
__global__ __launch_bounds__(256)
void qkv_mfma(const u16* __restrict__ xhi, const u16* __restrict__ xlo,
              const u16* __restrict__ whi, const u16* __restrict__ wlo,
              u16* __restrict__ qhi, u16* __restrict__ qlo,
              u16* __restrict__ khi, u16* __restrict__ klo,
              u16* __restrict__ vhi, u16* __restrict__ vlo)
{
    __shared__ __align__(16) u16 Ah[4096], Al[4096], Bh[4096], Bl[4096];  // [128][32]
    const int tid = threadIdx.x, lane = tid & 63, w = tid >> 6;
    const int l15 = lane & 15, l16 = lane >> 4;
    const int m0 = blockIdx.x * 128;
    const int ng = blockIdx.y * 128;
    const int tsel = ng >> 10;               // 0=q 1=k 2=v
    const int nloc0 = ng & 1023;
    const u16* __restrict__ Wh = whi + ((size_t)tsel << 20);
    const u16* __restrict__ Wl = wlo + ((size_t)tsel << 20);

    f32x4 acc[4][4];
    #pragma unroll
    for (int i = 0; i < 4; ++i)
        #pragma unroll
        for (int j = 0; j < 4; ++j) acc[i][j] = (f32x4){0.f, 0.f, 0.f, 0.f};

    for (int k0 = 0; k0 < 1024; k0 += 32) {
        __syncthreads();
        #pragma unroll
        for (int c = 0; c < 2; ++c) {
            const int idx  = w * 2 + c;              // wave-uniform chunk id 0..7
            const int trow = idx * 16 + (lane >> 2);
            const int tcol = (lane & 3) * 8;
            const size_t ga = (size_t)(m0 + trow) * 1024 + k0 + tcol;
            const size_t gb = (size_t)(nloc0 + trow) * 1024 + k0 + tcol;
            gll16(xhi + ga, (char*)Ah + idx * 1024);
            gll16(xlo + ga, (char*)Al + idx * 1024);
            gll16(Wh + gb,  (char*)Bh + idx * 1024);
            gll16(Wl + gb,  (char*)Bl + idx * 1024);
        }
        __syncthreads();
        const int mo = (w >> 1) * 64, no = (w & 1) * 64;
        bf16x8 a_h[4], a_l[4], b_h[4], b_l[4];
        #pragma unroll
        for (int f = 0; f < 4; ++f) {
            const int ao = (mo + f * 16 + l15) * 32 + l16 * 8;
            a_h[f] = *(const bf16x8*)&Ah[ao];
            a_l[f] = *(const bf16x8*)&Al[ao];
            const int bo = (no + f * 16 + l15) * 32 + l16 * 8;
            b_h[f] = *(const bf16x8*)&Bh[bo];
            b_l[f] = *(const bf16x8*)&Bl[bo];
        }
        #pragma unroll
        for (int i = 0; i < 4; ++i)
            #pragma unroll
            for (int j = 0; j < 4; ++j) {
                acc[i][j] = mfma16(a_h[i], b_h[j], acc[i][j]);
                acc[i][j] = mfma16(a_h[i], b_l[j], acc[i][j]);
                acc[i][j] = mfma16(a_l[i], b_h[j], acc[i][j]);
            }
    }

    const int mo = (w >> 1) * 64, no = (w & 1) * 64;
    const int hh = (nloc0 + no) >> 6;        // head (wave's 64-col block is head-aligned)
    if (tsel < 2) {
        u16* __restrict__ dh = tsel ? khi : qhi;
        u16* __restrict__ dl = tsel ? klo : qlo;
        const float scl = tsel ? 1.0f : 0.125f;   // fold 1/sqrt(hd) into q
        #pragma unroll
        for (int i = 0; i < 4; ++i)
            #pragma unroll
            for (int e = 0; e < 4; ++e) {
                const int row = m0 + mo + i * 16 + l16 * 4 + e;
                const int s = row & 2047, b = row >> 11;
                const size_t base = ((size_t)(b * NHEAD + hh) * S_LEN + s) * HDIM;
                #pragma unroll
                for (int j = 0; j < 2; ++j) {      // pair (d, d+32) = frags (j, j+2)
                    const int d = j * 16 + l15;    // d in [0,32)
                    // inv_freq in fp64 then rounded: <=1 ulp from true 10000^(-d/32),
                    // tracking the reference's fp32 pow as closely as possible.
                    const float inv = (float)exp((double)d * -0.28782313662425574);
                    const float ang = (float)s * inv;
                    const float sn = sinf(ang), cs = cosf(ang);
                    const float x1 = acc[i][j][e], x2 = acc[i][j + 2][e];
                    const float o1 = (x1 * cs - x2 * sn) * scl;
                    const float o2 = (x1 * sn + x2 * cs) * scl;
                    const u16 h1 = f2bf(o1), h2 = f2bf(o2);
                    dh[base + d]      = h1;
                    dl[base + d]      = f2bf(o1 - bf2f(h1));
                    dh[base + d + 32] = h2;
                    dl[base + d + 32] = f2bf(o2 - bf2f(h2));
                }
            }
    } else {
        #pragma unroll
        for (int i = 0; i < 4; ++i)
            #pragma unroll
            for (int e = 0; e < 4; ++e) {
                const int row = m0 + mo + i * 16 + l16 * 4 + e;
                const int s = row & 2047, b = row >> 11;
                const size_t base = ((size_t)(b * NHEAD + hh) * S_LEN + s) * HDIM;
                #pragma unroll
                for (int j = 0; j < 4; ++j) {
                    const float o = acc[i][j][e];
                    const u16 h1 = f2bf(o);
                    vhi[base + j * 16 + l15] = h1;
                    vlo[base + j * 16 + l15] = f2bf(o - bf2f(h1));
                }
            }
    }
}

// ---------------- 3. V transpose: [bh][s][d] -> [bh][d][s] ----------------
__global__ __launch_bounds__(256)
void vtrans(const u16* __restrict__ vhi, const u16* __restrict__ vlo,
            u16* __restrict__ vthi, u16* __restrict__ vtlo)
{
    __shared__ __align__(16) u16 T[64][72];
    const u16* __restrict__ src = blockIdx.z ? vlo : vhi;
    u16* __restrict__ dst = blockIdx.z ? vtlo : vthi;
    const int bh = blockIdx.y;
    const int s0 = blockIdx.x * 64;
    const int tid = threadIdx.x;
    #pragma unroll
    for (int p = 0; p < 2; ++p) {
        const int c = tid + p * 256;
        const int r = c >> 3, dc = (c & 7) * 8;
        *(uint4*)&T[r][dc] = *(const uint4*)&src[((size_t)bh * S_LEN + s0 + r) * HDIM + dc];
    }
    __syncthreads();
    #pragma unroll
    for (int p = 0; p < 2; ++p) {
        const int c = tid + p * 256;
        const int d = c >> 3, sc8 = (c & 7) * 8;
        __align__(16) u16 tmp[8];
        #pragma unroll
        for (int u = 0; u < 8; ++u) tmp[u] = T[sc8 + u][d];
        *(uint4*)&dst[((size_t)bh * HDIM + d) * S_LEN + s0 + sc8] = *(uint4*)tmp;
    }
}

// ---------------- 4. causal flash attention (hi/lo MFMA) ----------------
// grid (qt=32, bh=32), 256 thr = 4 waves, wave w owns q-rows [qt*64+16w, +16).
__global__ __launch_bounds__(256)
void attn_mfma(const u16* __restrict__ qhi, const u16* __restrict__ qlo,
               const u16* __restrict__ khi, const u16* __restrict__ klo,
               const u16* __restrict__ vthi, const u16* __restrict__ vtlo,
               u16* __restrict__ ohi, u16* __restrict__ olo)
{
    __shared__ __align__(16) u16 Kh[64][72], Kl[64][72], Vh[64][72], Vl[64][72];
    __shared__ __align__(16) float Pw[4][16][68];
    const int tid = threadIdx.x, lane = tid & 63, w = tid >> 6;
    const int l15 = lane & 15, l16 = lane >> 4;
    const int qt = blockIdx.x, bh = blockIdx.y;
    const size_t sbase = (size_t)bh * S_LEN * HDIM;   // [bh][s][d]
    const size_t dbase = (size_t)bh * HDIM * S_LEN;   // [bh][d][s]

    // Q fragments hoisted for the whole kernel (q pre-scaled by 1/8)
    bf16x8 q_h[2], q_l[2];
    {
        const int s = qt * 64 + w * 16 + l15;
        #pragma unroll
        for (int ks = 0; ks < 2; ++ks) {
            const size_t ga = sbase + (size_t)s * HDIM + ks * 32 + l16 * 8;
            q_h[ks] = *(const bf16x8*)&qhi[ga];
            q_l[ks] = *(const bf16x8*)&qlo[ga];
        }
    }

    f32x4 oacc[4];
    #pragma unroll
    for (int t = 0; t < 4; ++t) oacc[t] = (f32x4){0.f, 0.f, 0.f, 0.f};
    float m_i[4], l_i[4];
    #pragma unroll
    for (int e = 0; e < 4; ++e) { m_i[e] = -INFINITY; l_i[e] = 0.f; }

    for (int kt = 0; kt <= qt; ++kt) {
        __syncthreads();                       // protect LDS K/V reuse
        #pragma unroll
        for (int p = 0; p < 2; ++p) {          // reg-stage K and V^T tiles
            const int c = tid + p * 256;       // 512 16B-chunks per tensor
            const int r = c >> 3, dc = (c & 7) * 8;
            const size_t gk = sbase + (size_t)(kt * 64 + r) * HDIM + dc;
            *(uint4*)&Kh[r][dc] = *(const uint4*)&khi[gk];
            *(uint4*)&Kl[r][dc] = *(const uint4*)&klo[gk];
            const size_t gv = dbase + (size_t)r * S_LEN + kt * 64 + dc;
            *(uint4*)&Vh[r][dc] = *(const uint4*)&vthi[gv];
            *(uint4*)&Vl[r][dc] = *(const uint4*)&vtlo[gv];
        }
        __syncthreads();

        // QK^T: scores[16 q-rows][64 k-cols] per wave
        f32x4 st[4];
        #pragma unroll
        for (int t = 0; t < 4; ++t) st[t] = (f32x4){0.f, 0.f, 0.f, 0.f};
        #pragma unroll
        for (int t = 0; t < 4; ++t)
            #pragma unroll
            for (int ks = 0; ks < 2; ++ks) {
                const bf16x8 kf_h = *(const bf16x8*)&Kh[t * 16 + l15][ks * 32 + l16 * 8];
                const bf16x8 kf_l = *(const bf16x8*)&Kl[t * 16 + l15][ks * 32 + l16 * 8];
                st[t] = mfma16(q_h[ks], kf_h, st[t]);
                st[t] = mfma16(q_h[ks], kf_l, st[t]);
                st[t] = mfma16(q_l[ks], kf_h, st[t]);
            }
        if (kt == qt) {                        // causal mask inside diagonal tile
            #pragma unroll
            for (int t = 0; t < 4; ++t)
                #pragma unroll
                for (int e = 0; e < 4; ++e)
                    if (t * 16 + l15 > w * 16 + l16 * 4 + e) st[t][e] = -1e30f;
        }
        // online softmax (rows live in D-layout: row = 4*l16+e, 16 lanes share a row)
        #pragma unroll
        for (int e = 0; e < 4; ++e) {
            float mx = fmaxf(fmaxf(st[0][e], st[1][e]), fmaxf(st[2][e], st[3][e]));
            #pragma unroll
            for (int msk = 8; msk >= 1; msk >>= 1) mx = fmaxf(mx, __shfl_xor(mx, msk));
            const float mn = fmaxf(m_i[e], mx);
            const float scl = __expf(m_i[e] - mn);
            float rs = 0.f;
            #pragma unroll
            for (int t = 0; t < 4; ++t) {
                const float p = __expf(st[t][e] - mn);
                st[t][e] = p; rs += p;
            }
            #pragma unroll
            for (int msk = 8; msk >= 1; msk >>= 1) rs += __shfl_xor(rs, msk);
            l_i[e] = l_i[e] * scl + rs;
            m_i[e] = mn;
            #pragma unroll
            for (int t = 0; t < 4; ++t) oacc[t][e] *= scl;
        }
        // P: D-layout regs -> wave-private LDS -> A-operand layout + hi/lo split
        #pragma unroll
        for (int t = 0; t < 4; ++t)
            #pragma unroll
            for (int e = 0; e < 4; ++e)
                Pw[w][l16 * 4 + e][t * 16 + l15] = st[t][e];
        bf16x8 p_h[2], p_l[2];
        #pragma unroll
        for (int ks = 0; ks < 2; ++ks) {
            float pf[8];
            *(f32x4*)&pf[0] = *(const f32x4*)&Pw[w][l15][ks * 32 + l16 * 8];
            *(f32x4*)&pf[4] = *(const f32x4*)&Pw[w][l15][ks * 32 + l16 * 8 + 4];
            #pragma unroll
            for (int u = 0; u < 8; ++u) {
                const u16 hb = f2bf(pf[u]);
                p_h[ks][u] = (short)hb;
                p_l[ks][u] = (short)f2bf(pf[u] - bf2f(hb));
            }
        }
        // PV: out[m][d] += P[m][n] V[n][d]  (V^T tile, n contiguous)
        #pragma unroll
        for (int t = 0; t < 4; ++t)
            #pragma unroll
            for (int ks = 0; ks < 2; ++ks) {
                const bf16x8 vf_h = *(const bf16x8*)&Vh[t * 16 + l15][ks * 32 + l16 * 8];
                const bf16x8 vf_l = *(const bf16x8*)&Vl[t * 16 + l15][ks * 32 + l16 * 8];
                oacc[t] = mfma16(p_h[ks], vf_h, oacc[t]);
                oacc[t] = mfma16(p_h[ks], vf_l, oacc[t]);
                oacc[t] = mfma16(p_l[ks], vf_h, oacc[t]);
            }
    }
    // epilogue: normalize, split hi/lo, store [bh][s][d]
    #pragma unroll
    for (int e = 0; e < 4; ++e) {
        const float inv = 1.f / l_i[e];
        const int s = qt * 64 + w * 16 + l16 * 4 + e;
        #pragma unroll
        for (int t = 0; t < 4; ++t) {
            const float o = oacc[t][e] * inv;
            const size_t ga = sbase + (size_t)s * HDIM + t * 16 + l15;
            const u16 hb = f2bf(o);
            ohi[ga] = hb;
            olo[ga] = f2bf(o - bf2f(hb));
        }
    }
}

// ---------------- 5. output projection: out = attn_out @ Wo^T (fp32 out) ----------------
__global__ __launch_bounds__(256)
void proj_mfma(const u16* __restrict__ ahi, const u16* __restrict__ alo,
               const u16* __restrict__ wohi, const u16* __restrict__ wolo,
               float* __restrict__ out)
{
    __shared__ __align__(16) u16 Ah[4096], Al[4096], Bh[4096], Bl[4096];
    const int tid = threadIdx.x, lane = tid & 63, w = tid >> 6;
    const int l15 = lane & 15, l16 = lane >> 4;
    const int m0 = blockIdx.x * 128, n0 = blockIdx.y * 128;

    f32x4 acc[4][4];
    #pragma unroll
    for (int i = 0; i < 4; ++i)
        #pragma unroll
        for (int j = 0; j < 4; ++j) acc[i][j] = (f32x4){0.f, 0.f, 0.f, 0.f};

    for (int k0 = 0; k0 < 1024; k0 += 32) {
        __syncthreads();
        #pragma unroll
        for (int c = 0; c < 2; ++c) {
            const int idx  = w * 2 + c;
            const int trow = idx * 16 + (lane >> 2);
            const int tcol = (lane & 3) * 8;
            // A gathered from [bh][s][d]
            const int ri = m0 + trow;
            const int b = ri >> 11, s = ri & 2047;
            const int kc = k0 + tcol;
            const int hh = kc >> 6, dd = kc & 63;
            const size_t ga = ((size_t)(b * NHEAD + hh) * S_LEN + s) * HDIM + dd;
            const size_t gb = (size_t)(n0 + trow) * 1024 + k0 + tcol;
            gll16(ahi + ga,  (char*)Ah + idx * 1024);
            gll16(alo + ga,  (char*)Al + idx * 1024);
            gll16(wohi + gb, (char*)Bh + idx * 1024);
            gll16(wolo + gb, (char*)Bl + idx * 1024);
        }
        __syncthreads();
        const int mo = (w >> 1) * 64, no = (w & 1) * 64;
        bf16x8 a_h[4], a_l[4], b_h[4], b_l[4];
        #pragma unroll
        for (int f = 0; f < 4; ++f) {
            const int ao = (mo + f * 16 + l15) * 32 + l16 * 8;
            a_h[f] = *(const bf16x8*)&Ah[ao];
            a_l[f] = *(const bf16x8*)&Al[ao];
            const int bo = (no + f * 16 + l15) * 32 + l16 * 8;
            b_h[f] = *(const bf16x8*)&Bh[bo];
            b_l[f] = *(const bf16x8*)&Bl[bo];
        }
        #pragma unroll
        for (int i = 0; i < 4; ++i)
            #pragma unroll
            for (int j = 0; j < 4; ++j) {
                acc[i][j] = mfma16(a_h[i], b_h[j], acc[i][j]);
                acc[i][j] = mfma16(a_h[i], b_l[j], acc[i][j]);
                acc[i][j] = mfma16(a_l[i], b_h[j], acc[i][j]);
            }
    }
    const int mo = (w >> 1) * 64, no = (w & 1) * 64;
    #pragma unroll
    for (int i = 0; i < 4; ++i)
        #pragma unroll
        for (int e = 0; e < 4; ++e) {
            const int row = m0 + mo + i * 16 + l16 * 4 + e;
            #pragma unroll
            for (int j = 0; j < 4; ++j)
                out[(size_t)row * 1024 + n0 + no + j * 16 + l15] = acc[i][j][e];
        }
}

extern "C" void kernel_launch(void* const* d_in, const int* in_sizes, int n_in,
                              void* d_out, int out_size, void* d_ws, size_t ws_size,
                              hipStream_t stream)
{
    const float* x  = (const float*)d_in[0];
    const float* Wq = (const float*)d_in[1];
    const float* Wk = (const float*)d_in[2];
    const float* Wv = (const float*)d_in[3];
    const float* Wo = (const float*)d_in[4];
    float* out = (float*)d_out;

    char* ws = (char*)d_ws;
    const size_t MB = (size_t)1 << 20;
    u16* xhi  = (u16*)(ws +  0 * MB);   // 8 MB, reused as ohi after qkv
    u16* xlo  = (u16*)(ws +  8 * MB);   // 8 MB, reused as olo
    u16* whi  = (u16*)(ws + 16 * MB);   // 8 MB: [4][1024][1024] q,k,v,o
    u16* wlo  = (u16*)(ws + 24 * MB);   // 8 MB
    u16* qhi  = (u16*)(ws + 32 * MB);
    u16* qlo  = (u16*)(ws + 40 * MB);
    u16* khi  = (u16*)(ws + 48 * MB);
    u16* klo  = (u16*)(ws + 56 * MB);
    u16* vhi  = (u16*)(ws + 64 * MB);
    u16* vlo  = (u16*)(ws + 72 * MB);
    u16* vthi = (u16*)(ws + 80 * MB);
    u16* vtlo = (u16*)(ws + 88 * MB);   // total 96 MB

    split_convert<<<8192, 256, 0, stream>>>(x, Wq, Wk, Wv, Wo, xhi, xlo, whi, wlo);
    qkv_mfma<<<dim3(32, 24), 256, 0, stream>>>(xhi, xlo, whi, wlo,
                                               qhi, qlo, khi, klo, vhi, vlo);
    vtrans<<<dim3(32, NBH, 2), 256, 0, stream>>>(vhi, vlo, vthi, vtlo);
    attn_mfma<<<dim3(32, NBH), 256, 0, stream>>>(qhi, qlo, khi, klo, vthi, vtlo,
                                                 xhi, xlo);
    proj_mfma<<<dim3(32, 8), 256, 0, stream>>>(xhi, xlo,
                                               whi + ((size_t)3 << 20), wlo + ((size_t)3 << 20),
                                               out);
}

// Round 6
// 599.907 us; speedup vs baseline: 1.0001x; 1.0001x over previous
//
#include <hip/hip_runtime.h>
#include <math.h>
#include <stdint.h>

// AttentionMC on MI355X: x(2,2048,1024) fp32; Wq/Wk/Wv/Wo(1024,1024) fp32.
// Split-bf16 (hi/lo, 3-term) MFMA implementation: ~1e-3 absmax (passed R3).
// R4/R5: fix 28x HBM write amplification (scalar u16 scatter stores) via
// LDS-staged coalesced uint4 stores; V written pre-transposed (vtrans killed);
// attn q-tiles dispatched longest-first (causal load imbalance).
// Pipeline: split_convert -> qkv_mfma(+RoPE, +V^T) -> attn_mfma -> proj_mfma.
// ws (80 MB): xhi xlo | whi wlo | qhi qlo khi klo | vthi vtlo
//   (xhi/xlo reused as attn-out hi/lo after qkv consumes x).

#define S_LEN 2048
#define NHEAD 16
#define HDIM  64
#define NBH   32

typedef __attribute__((ext_vector_type(8))) short  bf16x8;
typedef __attribute__((ext_vector_type(4))) float  f32x4;
typedef unsigned short u16;
typedef unsigned int   u32;

__device__ __forceinline__ u16 f2bf(float f) {          // RNE fp32->bf16 bits
    u32 u = __float_as_uint(f);
    return (u16)((u + 0x7FFFu + ((u >> 16) & 1u)) >> 16);
}
__device__ __forceinline__ float bf2f(u16 s) {
    return __uint_as_float(((u32)s) << 16);
}
__device__ __forceinline__ f32x4 mfma16(bf16x8 a, bf16x8 b, f32x4 c) {
    return __builtin_amdgcn_mfma_f32_16x16x32_bf16(a, b, c, 0, 0, 0);
}
__device__ __forceinline__ void gll16(const void* g, void* l) {
    __builtin_amdgcn_global_load_lds((const __attribute__((address_space(1))) u32*)g,
                                     (__attribute__((address_space(3))) u32*)l, 16, 0, 0);
}

// ---------------- 1. fp32 -> bf16 hi/lo split for x and all weights ----------------
__global__ __launch_bounds__(256)
void split_convert(const float* __restrict__ x,
                   const float* __restrict__ Wq, const float* __restrict__ Wk,
                   const float* __restrict__ Wv, const float* __restrict__ Wo,
                   u16* __restrict__ xhi, u16* __restrict__ xlo,
                   u16* __restrict__ whi, u16* __restrict__ wlo)
{
    const int g = blockIdx.x * 256 + threadIdx.x;   // float4 index, 2M total
    const float* src; u16 *dhi, *dlo; int loc;
    if (g < 1048576) { src = x; dhi = xhi; dlo = xlo; loc = g; }
    else {
        const int r = g - 1048576;
        const int wsel = r >> 18;                   // 256K float4 per weight
        loc = r & 262143;
        src = (wsel == 0) ? Wq : (wsel == 1) ? Wk : (wsel == 2) ? Wv : Wo;
        dhi = whi + ((size_t)wsel << 20);
        dlo = wlo + ((size_t)wsel << 20);
    }
    const float4 v = reinterpret_cast<const float4*>(src)[loc];
    ushort4 hv, lv;
    hv.x = f2bf(v.x); lv.x = f2bf(v.x - bf2f(hv.x));
    hv.y = f2bf(v.y); lv.y = f2bf(v.y - bf2f(hv.y));
    hv.z = f2bf(v.z); lv.z = f2bf(v.z - bf2f(hv.z));
    hv.w = f2bf(v.w); lv.w = f2bf(v.w - bf2f(hv.w));
    reinterpret_cast<ushort4*>(dhi)[loc] = hv;
    reinterpret_cast<ushort4*>(dlo)[loc] = lv;
}

// ---------------- 2. QKV projection GEMM (hi/lo MFMA) + RoPE + V^T epilogue ----------------
// M=4096, Nglobal=3072 (q|k|v), K=1024. 128x128 tile, BK=32, 4 waves (64x64 each).
// LDS: main loop 32 KB staging (Ah|Al|Bh|Bl), epilogue reuses as 4x10 KB wave chunks.
__global__ __launch_bounds__(256)
void qkv_mfma(const u16* __restrict__ xhi, const u16* __restrict__ xlo,
              const u16* __restrict__ whi, const u16* __restrict__ wlo,
              u16* __restrict__ qhi, u16* __restrict__ qlo,
              u16* __restrict__ khi, u16* __restrict__ klo,
              u16* __restrict__ vthi, u16* __restrict__ vtlo)
{
    __shared__ __align__(16) u16 SMEM[20480];   // 40960 B
    const int tid = threadIdx.x, lane = tid & 63, w = tid >> 6;
    const int l15 = lane & 15, l16 = lane >> 4;
    const int m0 = blockIdx.x * 128;
    const int ng = blockIdx.y * 128;
    const int tsel = ng >> 10;               // 0=q 1=k 2=v
    const int nloc0 = ng & 1023;
    const u16* __restrict__ Wh = whi + ((size_t)tsel << 20);
    const u16* __restrict__ Wl = wlo + ((size_t)tsel << 20);

    f32x4 acc[4][4];
    #pragma unroll
    for (int i = 0; i < 4; ++i)
        #pragma unroll
        for (int j = 0; j < 4; ++j) acc[i][j] = (f32x4){0.f, 0.f, 0.f, 0.f};

    for (int k0 = 0; k0 < 1024; k0 += 32) {
        __syncthreads();
        #pragma unroll
        for (int c = 0; c < 2; ++c) {
            const int idx  = w * 2 + c;              // wave-uniform chunk id 0..7
            const int trow = idx * 16 + (lane >> 2);
            const int tcol = (lane & 3) * 8;
            const size_t ga = (size_t)(m0 + trow) * 1024 + k0 + tcol;
            const size_t gb = (size_t)(nloc0 + trow) * 1024 + k0 + tcol;
            gll16(xhi + ga, (char*)SMEM + idx * 1024);            // Ah @ 0
            gll16(xlo + ga, (char*)SMEM +  8192 + idx * 1024);    // Al
            gll16(Wh + gb,  (char*)SMEM + 16384 + idx * 1024);    // Bh
            gll16(Wl + gb,  (char*)SMEM + 24576 + idx * 1024);    // Bl
        }
        __syncthreads();
        const int mo = (w >> 1) * 64, no = (w & 1) * 64;
        bf16x8 a_h[4], a_l[4], b_h[4], b_l[4];
        #pragma unroll
        for (int f = 0; f < 4; ++f) {
            const int ao = (mo + f * 16 + l15) * 32 + l16 * 8;
            a_h[f] = *(const bf16x8*)&SMEM[ao];
            a_l[f] = *(const bf16x8*)&SMEM[4096 + ao];
            const int bo = (no + f * 16 + l15) * 32 + l16 * 8;
            b_h[f] = *(const bf16x8*)&SMEM[8192 + bo];
            b_l[f] = *(const bf16x8*)&SMEM[12288 + bo];
        }
        #pragma unroll
        for (int i = 0; i < 4; ++i)
            #pragma unroll
            for (int j = 0; j < 4; ++j) {
                acc[i][j] = mfma16(a_h[i], b_h[j], acc[i][j]);
                acc[i][j] = mfma16(a_h[i], b_l[j], acc[i][j]);
                acc[i][j] = mfma16(a_l[i], b_h[j], acc[i][j]);
            }
    }

    // ---- epilogue: LDS-staged, fully-coalesced uint4 stores ----
    __syncthreads();                         // all waves done reading SMEM
    const int mo = (w >> 1) * 64, no = (w & 1) * 64;
    const int hh = (nloc0 + no) >> 6;        // head (wave's 64-col block is head-aligned)
    const int mrow = m0 + mo;
    const int b = mrow >> 11, sb0 = mrow & 2047;
    u16* const chunk = SMEM + w * 5120;      // 10240 B per wave

    if (tsel < 2) {
        u16* __restrict__ dh = tsel ? khi : qhi;
        u16* __restrict__ dl = tsel ? klo : qlo;
        const float scl = tsel ? 1.0f : 0.125f;   // fold 1/sqrt(hd) into q
        // inv_freq: <=1 ulp of 10000^(-d/32); only 2 distinct d per thread
        const float inv0 = (float)exp((double)l15        * -0.28782313662425574);
        const float inv1 = (float)exp((double)(l15 + 16) * -0.28782313662425574);
        u16* const Thi = chunk;              // [32][72]
        u16* const Tlo = chunk + 2304;
        #pragma unroll
        for (int half = 0; half < 2; ++half) {
            #pragma unroll
            for (int i2 = 0; i2 < 2; ++i2) {
                const int i = half * 2 + i2;
                #pragma unroll
                for (int e = 0; e < 4; ++e) {
                    const int rl = i2 * 16 + l16 * 4 + e;     // row within half-tile
                    const int s = sb0 + half * 32 + rl;
                    #pragma unroll
                    for (int j = 0; j < 2; ++j) {             // pair (d, d+32) = frags (j, j+2)
                        const float inv = j ? inv1 : inv0;
                        const float ang = (float)s * inv;
                        const float sn = sinf(ang), cs = cosf(ang);
                        const float x1 = acc[i][j][e], x2 = acc[i][j + 2][e];
                        const float o1 = (x1 * cs - x2 * sn) * scl;
                        const float o2 = (x1 * sn + x2 * cs) * scl;
                        const u16 h1 = f2bf(o1), h2 = f2bf(o2);
                        Thi[rl * 72 + j * 16 + l15]       = h1;
                        Tlo[rl * 72 + j * 16 + l15]       = f2bf(o1 - bf2f(h1));
                        Thi[rl * 72 + (j + 2) * 16 + l15] = h2;
                        Tlo[rl * 72 + (j + 2) * 16 + l15] = f2bf(o2 - bf2f(h2));
                    }
                }
            }
            #pragma unroll
            for (int p = 0; p < 4; ++p) {    // 32 rows x 128B, full lines
                const int slot = p * 64 + lane;
                const int rr = slot >> 3, c8 = (slot & 7) * 8;
                const size_t ga = (((size_t)(b * NHEAD + hh) * S_LEN) + sb0 + half * 32 + rr) * HDIM + c8;
                *(uint4*)&dh[ga] = *(const uint4*)&Thi[rr * 72 + c8];
                *(uint4*)&dl[ga] = *(const uint4*)&Tlo[rr * 72 + c8];
            }
        }
    } else {
        // V: stage transposed (d-major) and store directly to V^T [bh][d][s]
        u16* const Thi = chunk;              // [64][40]
        u16* const Tlo = chunk + 2560;
        #pragma unroll
        for (int half = 0; half < 2; ++half) {
            #pragma unroll
            for (int i2 = 0; i2 < 2; ++i2) {
                const int i = half * 2 + i2;
                #pragma unroll
                for (int e = 0; e < 4; ++e) {
                    const int rl = i2 * 16 + l16 * 4 + e;     // s within half-tile
                    #pragma unroll
                    for (int j = 0; j < 4; ++j) {
                        const float o = acc[i][j][e];
                        const u16 hb = f2bf(o);
                        Thi[(j * 16 + l15) * 40 + rl] = hb;
                        Tlo[(j * 16 + l15) * 40 + rl] = f2bf(o - bf2f(hb));
                    }
                }
            }
            #pragma unroll
            for (int p = 0; p < 4; ++p) {    // 64 d-rows x 64B
                const int slot = p * 64 + lane;
                const int dd = slot >> 2, s8 = (slot & 3) * 8;
                const size_t ga = (((size_t)(b * NHEAD + hh) * HDIM) + dd) * S_LEN + sb0 + half * 32 + s8;
                *(uint4*)&vthi[ga] = *(const uint4*)&Thi[dd * 40 + s8];
                *(uint4*)&vtlo[ga] = *(const uint4*)&Tlo[dd * 40 + s8];
            }
        }
    }
}

// ---------------- 3. causal flash attention (hi/lo MFMA) ----------------
// grid (qt=32, bh=32), 256 thr = 4 waves, wave w owns q-rows [qt*64+16w, +16).
// qt dispatched longest-first (qt = 31 - blockIdx.x) for causal load balance.
// LDS 54272 B flat: KH|KL|VH|VL (u16 [64][72] each) | PW (float [4][16][68]).
__global__ __launch_bounds__(256)
void attn_mfma(const u16* __restrict__ qhi, const u16* __restrict__ qlo,
               const u16* __restrict__ khi, const u16* __restrict__ klo,
               const u16* __restrict__ vthi, const u16* __restrict__ vtlo,
               u16* __restrict__ ohi, u16* __restrict__ olo)
{
    __shared__ __align__(16) u16 AS[27136];
    u16* const KH = AS;              // 4608 u16
    u16* const KL = AS + 4608;
    u16* const VH = AS + 9216;
    u16* const VL = AS + 13824;
    float* const PW = (float*)(AS + 18432);   // [4][16][68]
    const int tid = threadIdx.x, lane = tid & 63, w = tid >> 6;
    const int l15 = lane & 15, l16 = lane >> 4;
    const int qt = 31 - blockIdx.x;           // longest blocks first
    const int bh = blockIdx.y;
    const size_t sbase = (size_t)bh * S_LEN * HDIM;   // [bh][s][d]
    const size_t dbase = (size_t)bh * HDIM * S_LEN;   // [bh][d][s]
    float* const pw = PW + w * 1088;

    // Q fragments hoisted for the whole kernel (q pre-scaled by 1/8)
    bf16x8 q_h[2], q_l[2];
    {
        const int s = qt * 64 + w * 16 + l15;
        #pragma unroll
        for (int ks = 0; ks < 2; ++ks) {
            const size_t ga = sbase + (size_t)s * HDIM + ks * 32 + l16 * 8;
            q_h[ks] = *(const bf16x8*)&qhi[ga];
            q_l[ks] = *(const bf16x8*)&qlo[ga];
        }
    }

    f32x4 oacc[4];
    #pragma unroll
    for (int t = 0; t < 4; ++t) oacc[t] = (f32x4){0.f, 0.f, 0.f, 0.f};
    float m_i[4], l_i[4];
    #pragma unroll
    for (int e = 0; e < 4; ++e) { m_i[e] = -INFINITY; l_i[e] = 0.f; }

    for (int kt = 0; kt <= qt; ++kt) {
        __syncthreads();                       // protect LDS K/V reuse
        #pragma unroll
        for (int p = 0; p < 2; ++p) {          // reg-stage K and V^T tiles
            const int c = tid + p * 256;       // 512 16B-chunks per tensor
            const int r = c >> 3, dc = (c & 7) * 8;
            const size_t gk = sbase + (size_t)(kt * 64 + r) * HDIM + dc;
            *(uint4*)&KH[r * 72 + dc] = *(const uint4*)&khi[gk];
            *(uint4*)&KL[r * 72 + dc] = *(const uint4*)&klo[gk];
            const size_t gv = dbase + (size_t)r * S_LEN + kt * 64 + dc;
            *(uint4*)&VH[r * 72 + dc] = *(const uint4*)&vthi[gv];
            *(uint4*)&VL[r * 72 + dc] = *(const uint4*)&vtlo[gv];
        }
        __syncthreads();

        // QK^T: scores[16 q-rows][64 k-cols] per wave
        f32x4 st[4];
        #pragma unroll
        for (int t = 0; t < 4; ++t) st[t] = (f32x4){0.f, 0.f, 0.f, 0.f};
        #pragma unroll
        for (int t = 0; t < 4; ++t)
            #pragma unroll
            for (int ks = 0; ks < 2; ++ks) {
                const bf16x8 kf_h = *(const bf16x8*)&KH[(t * 16 + l15) * 72 + ks * 32 + l16 * 8];
                const bf16x8 kf_l = *(const bf16x8*)&KL[(t * 16 + l15) * 72 + ks * 32 + l16 * 8];
                st[t] = mfma16(q_h[ks], kf_h, st[t]);
                st[t] = mfma16(q_h[ks], kf_l, st[t]);
                st[t] = mfma16(q_l[ks], kf_h, st[t]);
            }
        if (kt == qt) {                        // causal mask inside diagonal tile
            #pragma unroll
            for (int t = 0; t < 4; ++t)
                #pragma unroll
                for (int e = 0; e < 4; ++e)
                    if (t * 16 + l15 > w * 16 + l16 * 4 + e) st[t][e] = -1e30f;
        }
        // online softmax (rows live in D-layout: row = 4*l16+e, 16 lanes share a row)
        #pragma unroll
        for (int e = 0; e < 4; ++e) {
            float mx = fmaxf(fmaxf(st[0][e], st[1][e]), fmaxf(st[2][e], st[3][e]));
            #pragma unroll
            for (int msk = 8; msk >= 1; msk >>= 1) mx = fmaxf(mx, __shfl_xor(mx, msk));
            const float mn = fmaxf(m_i[e], mx);
            const float scl = __expf(m_i[e] - mn);
            float rs = 0.f;
            #pragma unroll
            for (int t = 0; t < 4; ++t) {
                const float p = __expf(st[t][e] - mn);
                st[t][e] = p; rs += p;
            }
            #pragma unroll
            for (int msk = 8; msk >= 1; msk >>= 1) rs += __shfl_xor(rs, msk);
            l_i[e] = l_i[e] * scl + rs;
            m_i[e] = mn;
            #pragma unroll
            for (int t = 0; t < 4; ++t) oacc[t][e] *= scl;
        }
        // P: D-layout regs -> wave-private LDS -> A-operand layout + hi/lo split
        #pragma unroll
        for (int t = 0; t < 4; ++t)
            #pragma unroll
            for (int e = 0; e < 4; ++e)
                pw[(l16 * 4 + e) * 68 + t * 16 + l15] = st[t][e];
        bf16x8 p_h[2], p_l[2];
        #pragma unroll
        for (int ks = 0; ks < 2; ++ks) {
            float pf[8];
            *(f32x4*)&pf[0] = *(const f32x4*)&pw[l15 * 68 + ks * 32 + l16 * 8];
            *(f32x4*)&pf[4] = *(const f32x4*)&pw[l15 * 68 + ks * 32 + l16 * 8 + 4];
            #pragma unroll
            for (int u = 0; u < 8; ++u) {
                const u16 hb = f2bf(pf[u]);
                p_h[ks][u] = (short)hb;
                p_l[ks][u] = (short)f2bf(pf[u] - bf2f(hb));
            }
        }
        // PV: out[m][d] += P[m][n] V[n][d]  (V^T tile, n contiguous)
        #pragma unroll
        for (int t = 0; t < 4; ++t)
            #pragma unroll
            for (int ks = 0; ks < 2; ++ks) {
                const bf16x8 vf_h = *(const bf16x8*)&VH[(t * 16 + l15) * 72 + ks * 32 + l16 * 8];
                const bf16x8 vf_l = *(const bf16x8*)&VL[(t * 16 + l15) * 72 + ks * 32 + l16 * 8];
                oacc[t] = mfma16(p_h[ks], vf_h, oacc[t]);
                oacc[t] = mfma16(p_h[ks], vf_l, oacc[t]);
                oacc[t] = mfma16(p_l[ks], vf_h, oacc[t]);
            }
    }
    // ---- epilogue: normalize, split hi/lo, LDS-staged coalesced store ----
    __syncthreads();                          // K/V LDS dead; alias staging over it
    u16* const Ohi = AS + w * 2304;           // [16][72] per wave
    u16* const Olo = Ohi + 1152;
    #pragma unroll
    for (int e = 0; e < 4; ++e) {
        const float invl = 1.f / l_i[e];
        const int rl = l16 * 4 + e;
        #pragma unroll
        for (int t = 0; t < 4; ++t) {
            const float o = oacc[t][e] * invl;
            const u16 hb = f2bf(o);
            Ohi[rl * 72 + t * 16 + l15] = hb;
            Olo[rl * 72 + t * 16 + l15] = f2bf(o - bf2f(hb));
        }
    }
    #pragma unroll
    for (int p = 0; p < 2; ++p) {             // 16 rows x 128B, full lines
        const int slot = p * 64 + lane;
        const int rr = slot >> 3, c8 = (slot & 7) * 8;
        const size_t ga = sbase + (size_t)(qt * 64 + w * 16 + rr) * HDIM + c8;
        *(uint4*)&ohi[ga] = *(const uint4*)&Ohi[rr * 72 + c8];
        *(uint4*)&olo[ga] = *(const uint4*)&Olo[rr * 72 + c8];
    }
}

// ---------------- 4. output projection: out = attn_out @ Wo^T (fp32 out) ----------------
__global__ __launch_bounds__(256)
void proj_mfma(const u16* __restrict__ ahi, const u16* __restrict__ alo,
               const u16* __restrict__ wohi, const u16* __restrict__ wolo,
               float* __restrict__ out)
{
    __shared__ __align__(16) u16 Ah[4096], Al[4096], Bh[4096], Bl[4096];
    const int tid = threadIdx.x, lane = tid & 63, w = tid >> 6;
    const int l15 = lane & 15, l16 = lane >> 4;
    const int m0 = blockIdx.x * 128, n0 = blockIdx.y * 128;

    f32x4 acc[4][4];
    #pragma unroll
    for (int i = 0; i < 4; ++i)
        #pragma unroll
        for (int j = 0; j < 4; ++j) acc[i][j] = (f32x4){0.f, 0.f, 0.f, 0.f};

    for (int k0 = 0; k0 < 1024; k0 += 32) {
        __syncthreads();
        #pragma unroll
        for (int c = 0; c < 2; ++c) {
            const int idx  = w * 2 + c;
            const int trow = idx * 16 + (lane >> 2);
            const int tcol = (lane & 3) * 8;
            // A gathered from [bh][s][d]
            const int ri = m0 + trow;
            const int b = ri >> 11, s = ri & 2047;
            const int kc = k0 + tcol;
            const int hh = kc >> 6, dd = kc & 63;
            const size_t ga = ((size_t)(b * NHEAD + hh) * S_LEN + s) * HDIM + dd;
            const size_t gb = (size_t)(n0 + trow) * 1024 + k0 + tcol;
            gll16(ahi + ga,  (char*)Ah + idx * 1024);
            gll16(alo + ga,  (char*)Al + idx * 1024);
            gll16(wohi + gb, (char*)Bh + idx * 1024);
            gll16(wolo + gb, (char*)Bl + idx * 1024);
        }
        __syncthreads();
        const int mo = (w >> 1) * 64, no = (w & 1) * 64;
        bf16x8 a_h[4], a_l[4], b_h[4], b_l[4];
        #pragma unroll
        for (int f = 0; f < 4; ++f) {
            const int ao = (mo + f * 16 + l15) * 32 + l16 * 8;
            a_h[f] = *(const bf16x8*)&Ah[ao];
            a_l[f] = *(const bf16x8*)&Al[ao];
            const int bo = (no + f * 16 + l15) * 32 + l16 * 8;
            b_h[f] = *(const bf16x8*)&Bh[bo];
            b_l[f] = *(const bf16x8*)&Bl[bo];
        }
        #pragma unroll
        for (int i = 0; i < 4; ++i)
            #pragma unroll
            for (int j = 0; j < 4; ++j) {
                acc[i][j] = mfma16(a_h[i], b_h[j], acc[i][j]);
                acc[i][j] = mfma16(a_h[i], b_l[j], acc[i][j]);
                acc[i][j] = mfma16(a_l[i], b_h[j], acc[i][j]);
            }
    }
    const int mo = (w >> 1) * 64, no = (w & 1) * 64;
    #pragma unroll
    for (int i = 0; i < 4; ++i)
        #pragma unroll
        for (int e = 0; e < 4; ++e) {
            const int row = m0 + mo + i * 16 + l16 * 4 + e;
            #pragma unroll
            for (int j = 0; j < 4; ++j)
                out[(size_t)row * 1024 + n0 + no + j * 16 + l15] = acc[i][j][e];
        }
}

extern "C" void kernel_launch(void* const* d_in, const int* in_sizes, int n_in,
                              void* d_out, int out_size, void* d_ws, size_t ws_size,
                              hipStream_t stream)
{
    const float* x  = (const float*)d_in[0];
    const float* Wq = (const float*)d_in[1];
    const float* Wk = (const float*)d_in[2];
    const float* Wv = (const float*)d_in[3];
    const float* Wo = (const float*)d_in[4];
    float* out = (float*)d_out;

    char* ws = (char*)d_ws;
    const size_t MB = (size_t)1 << 20;
    u16* xhi  = (u16*)(ws +  0 * MB);   // 8 MB, reused as attn-out hi
    u16* xlo  = (u16*)(ws +  8 * MB);   // 8 MB, reused as attn-out lo
    u16* whi  = (u16*)(ws + 16 * MB);   // 8 MB: [4][1024][1024] q,k,v,o
    u16* wlo  = (u16*)(ws + 24 * MB);   // 8 MB
    u16* qhi  = (u16*)(ws + 32 * MB);
    u16* qlo  = (u16*)(ws + 40 * MB);
    u16* khi  = (u16*)(ws + 48 * MB);
    u16* klo  = (u16*)(ws + 56 * MB);
    u16* vthi = (u16*)(ws + 64 * MB);   // [bh][d][s]
    u16* vtlo = (u16*)(ws + 72 * MB);   // total 80 MB

    split_convert<<<8192, 256, 0, stream>>>(x, Wq, Wk, Wv, Wo, xhi, xlo, whi, wlo);
    qkv_mfma<<<dim3(32, 24), 256, 0, stream>>>(xhi, xlo, whi, wlo,
                                               qhi, qlo, khi, klo, vthi, vtlo);
    attn_mfma<<<dim3(32, NBH), 256, 0, stream>>>(qhi, qlo, khi, klo, vthi, vtlo,
                                                 xhi, xlo);
    proj_mfma<<<dim3(32, 8), 256, 0, stream>>>(xhi, xlo,
                                               whi + ((size_t)3 << 20), wlo + ((size_t)3 << 20),
                                               out);
}

// Round 8
// 568.902 us; speedup vs baseline: 1.0546x; 1.0545x over previous
//
#include <hip/hip_runtime.h>
#include <math.h>
#include <stdint.h>

// AttentionMC on MI355X: x(2,2048,1024) fp32; Wq/Wk/Wv/Wo(1024,1024) fp32.
// Split-bf16 (hi/lo, 3-term) MFMA implementation: absmax 9.77e-4 (passed R3/R5).
// R6/R7: R5's counters showed qkv WRITE_SIZE ~1.33GB tracks the K-loop's
// global_load_lds volume (786MB/dispatch), not the stores -> replace gll16
// with reg-staged ds_write_b128 + 2-phase prefetch in qkv/proj. attn already
// reg-stages. All arithmetic byte-identical to R5.
// Pipeline: split_convert -> qkv_mfma(+RoPE, +V^T) -> attn_mfma -> proj_mfma.
// ws (80 MB): xhi xlo | whi wlo | qhi qlo khi klo | vthi vtlo
//   (xhi/xlo reused as attn-out hi/lo after qkv consumes x).

#define S_LEN 2048
#define NHEAD 16
#define HDIM  64
#define NBH   32

typedef __attribute__((ext_vector_type(8))) short  bf16x8;
typedef __attribute__((ext_vector_type(4))) float  f32x4;
typedef unsigned short u16;
typedef unsigned int   u32;

__device__ __forceinline__ u16 f2bf(float f) {          // RNE fp32->bf16 bits
    u32 u = __float_as_uint(f);
    return (u16)((u + 0x7FFFu + ((u >> 16) & 1u)) >> 16);
}
__device__ __forceinline__ float bf2f(u16 s) {
    return __uint_as_float(((u32)s) << 16);
}
__device__ __forceinline__ f32x4 mfma16(bf16x8 a, bf16x8 b, f32x4 c) {
    return __builtin_amdgcn_mfma_f32_16x16x32_bf16(a, b, c, 0, 0, 0);
}

// ---------------- 1. fp32 -> bf16 hi/lo split for x and all weights ----------------
__global__ __launch_bounds__(256)
void split_convert(const float* __restrict__ x,
                   const float* __restrict__ Wq, const float* __restrict__ Wk,
                   const float* __restrict__ Wv, const float* __restrict__ Wo,
                   u16* __restrict__ xhi, u16* __restrict__ xlo,
                   u16* __restrict__ whi, u16* __restrict__ wlo)
{
    const int g = blockIdx.x * 256 + threadIdx.x;   // float4 index, 2M total
    const float* src; u16 *dhi, *dlo; int loc;
    if (g < 1048576) { src = x; dhi = xhi; dlo = xlo; loc = g; }
    else {
        const int r = g - 1048576;
        const int wsel = r >> 18;                   // 256K float4 per weight
        loc = r & 262143;
        src = (wsel == 0) ? Wq : (wsel == 1) ? Wk : (wsel == 2) ? Wv : Wo;
        dhi = whi + ((size_t)wsel << 20);
        dlo = wlo + ((size_t)wsel << 20);
    }
    const float4 v = reinterpret_cast<const float4*>(src)[loc];
    ushort4 hv, lv;
    hv.x = f2bf(v.x); lv.x = f2bf(v.x - bf2f(hv.x));
    hv.y = f2bf(v.y); lv.y = f2bf(v.y - bf2f(hv.y));
    hv.z = f2bf(v.z); lv.z = f2bf(v.z - bf2f(hv.z));
    hv.w = f2bf(v.w); lv.w = f2bf(v.w - bf2f(hv.w));
    reinterpret_cast<ushort4*>(dhi)[loc] = hv;
    reinterpret_cast<ushort4*>(dlo)[loc] = lv;
}

// ---------------- 2. QKV projection GEMM (hi/lo MFMA) + RoPE + V^T epilogue ----------------
// M=4096, Nglobal=3072 (q|k|v), K=1024. 128x128 tile, BK=32, 4 waves (64x64 each).
// Reg-staged LDS fill (NO global_load_lds): thread tid stages slots {tid, tid+256}
// of 512 uint4 per tensor-pair layout [128 rows][32 u16]; 2-phase prefetch.
__global__ __launch_bounds__(256)
void qkv_mfma(const u16* __restrict__ xhi, const u16* __restrict__ xlo,
              const u16* __restrict__ whi, const u16* __restrict__ wlo,
              u16* __restrict__ qhi, u16* __restrict__ qlo,
              u16* __restrict__ khi, u16* __restrict__ klo,
              u16* __restrict__ vthi, u16* __restrict__ vtlo)
{
    __shared__ __align__(16) u16 SMEM[20480];   // 40960 B: Ah|Al|Bh|Bl @ 0/4096/8192/12288 u16
    const int tid = threadIdx.x, lane = tid & 63, w = tid >> 6;
    const int l15 = lane & 15, l16 = lane >> 4;
    const int m0 = blockIdx.x * 128;
    const int ng = blockIdx.y * 128;
    const int tsel = ng >> 10;               // 0=q 1=k 2=v
    const int nloc0 = ng & 1023;
    const u16* __restrict__ Wh = whi + ((size_t)tsel << 20);
    const u16* __restrict__ Wl = wlo + ((size_t)tsel << 20);

    // staging geometry: slot s -> row = s>>2 (0..127), col c0 = (s&3)*8 u16
    const int r0 = tid >> 2, r1 = r0 + 64;
    const int c0 = (tid & 3) * 8;

    f32x4 acc[4][4];
    #pragma unroll
    for (int i = 0; i < 4; ++i)
        #pragma unroll
        for (int j = 0; j < 4; ++j) acc[i][j] = (f32x4){0.f, 0.f, 0.f, 0.f};

    // prologue: load k-tile 0 into regs
    uint4 Ah0, Ah1, Al0, Al1, Bh0, Bh1, Bl0, Bl1;
    {
        const size_t a0 = (size_t)(m0 + r0) * 1024 + c0;
        const size_t a1 = (size_t)(m0 + r1) * 1024 + c0;
        const size_t b0 = (size_t)(nloc0 + r0) * 1024 + c0;
        const size_t b1 = (size_t)(nloc0 + r1) * 1024 + c0;
        Ah0 = *(const uint4*)&xhi[a0]; Ah1 = *(const uint4*)&xhi[a1];
        Al0 = *(const uint4*)&xlo[a0]; Al1 = *(const uint4*)&xlo[a1];
        Bh0 = *(const uint4*)&Wh[b0];  Bh1 = *(const uint4*)&Wh[b1];
        Bl0 = *(const uint4*)&Wl[b0];  Bl1 = *(const uint4*)&Wl[b1];
    }

    for (int k0 = 0; k0 < 1024; k0 += 32) {
        __syncthreads();                          // prev tile's frag reads done
        *(uint4*)&SMEM[        r0 * 32 + c0] = Ah0;
        *(uint4*)&SMEM[        r1 * 32 + c0] = Ah1;
        *(uint4*)&SMEM[ 4096 + r0 * 32 + c0] = Al0;
        *(uint4*)&SMEM[ 4096 + r1 * 32 + c0] = Al1;
        *(uint4*)&SMEM[ 8192 + r0 * 32 + c0] = Bh0;
        *(uint4*)&SMEM[ 8192 + r1 * 32 + c0] = Bh1;
        *(uint4*)&SMEM[12288 + r0 * 32 + c0] = Bl0;
        *(uint4*)&SMEM[12288 + r1 * 32 + c0] = Bl1;
        __syncthreads();                          // tile visible to all waves
        if (k0 + 32 < 1024) {                     // prefetch next tile under MFMA
            const int kn = k0 + 32;
            const size_t a0 = (size_t)(m0 + r0) * 1024 + kn + c0;
            const size_t a1 = (size_t)(m0 + r1) * 1024 + kn + c0;
            const size_t b0 = (size_t)(nloc0 + r0) * 1024 + kn + c0;
            const size_t b1 = (size_t)(nloc0 + r1) * 1024 + kn + c0;
            Ah0 = *(const uint4*)&xhi[a0]; Ah1 = *(const uint4*)&xhi[a1];
            Al0 = *(const uint4*)&xlo[a0]; Al1 = *(const uint4*)&xlo[a1];
            Bh0 = *(const uint4*)&Wh[b0];  Bh1 = *(const uint4*)&Wh[b1];
            Bl0 = *(const uint4*)&Wl[b0];  Bl1 = *(const uint4*)&Wl[b1];
        }
        const int mo = (w >> 1) * 64, no = (w & 1) * 64;
        bf16x8 a_h[4], a_l[4], b_h[4], b_l[4];
        #pragma unroll
        for (int f = 0; f < 4; ++f) {
            const int ao = (mo + f * 16 + l15) * 32 + l16 * 8;
            a_h[f] = *(const bf16x8*)&SMEM[ao];
            a_l[f] = *(const bf16x8*)&SMEM[4096 + ao];
            const int bo = (no + f * 16 + l15) * 32 + l16 * 8;
            b_h[f] = *(const bf16x8*)&SMEM[8192 + bo];
            b_l[f] = *(const bf16x8*)&SMEM[12288 + bo];
        }
        #pragma unroll
        for (int i = 0; i < 4; ++i)
            #pragma unroll
            for (int j = 0; j < 4; ++j) {
                acc[i][j] = mfma16(a_h[i], b_h[j], acc[i][j]);
                acc[i][j] = mfma16(a_h[i], b_l[j], acc[i][j]);
                acc[i][j] = mfma16(a_l[i], b_h[j], acc[i][j]);
            }
    }

    // ---- epilogue: LDS-staged, fully-coalesced uint4 stores ----
    __syncthreads();                         // all waves done reading SMEM
    const int mo = (w >> 1) * 64, no = (w & 1) * 64;
    const int hh = (nloc0 + no) >> 6;        // head (wave's 64-col block is head-aligned)
    const int mrow = m0 + mo;
    const int b = mrow >> 11, sb0 = mrow & 2047;
    u16* const chunk = SMEM + w * 5120;      // 10240 B per wave

    if (tsel < 2) {
        u16* __restrict__ dh = tsel ? khi : qhi;
        u16* __restrict__ dl = tsel ? klo : qlo;
        const float scl = tsel ? 1.0f : 0.125f;   // fold 1/sqrt(hd) into q
        // inv_freq: <=1 ulp of 10000^(-d/32); only 2 distinct d per thread
        const float inv0 = (float)exp((double)l15        * -0.28782313662425574);
        const float inv1 = (float)exp((double)(l15 + 16) * -0.28782313662425574);
        u16* const Thi = chunk;              // [32][72]
        u16* const Tlo = chunk + 2304;
        #pragma unroll
        for (int half = 0; half < 2; ++half) {
            #pragma unroll
            for (int i2 = 0; i2 < 2; ++i2) {
                const int i = half * 2 + i2;
                #pragma unroll
                for (int e = 0; e < 4; ++e) {
                    const int rl = i2 * 16 + l16 * 4 + e;     // row within half-tile
                    const int s = sb0 + half * 32 + rl;
                    #pragma unroll
                    for (int j = 0; j < 2; ++j) {             // pair (d, d+32) = frags (j, j+2)
                        const float inv = j ? inv1 : inv0;
                        const float ang = (float)s * inv;
                        const float sn = sinf(ang), cs = cosf(ang);
                        const float x1 = acc[i][j][e], x2 = acc[i][j + 2][e];
                        const float o1 = (x1 * cs - x2 * sn) * scl;
                        const float o2 = (x1 * sn + x2 * cs) * scl;
                        const u16 h1 = f2bf(o1), h2 = f2bf(o2);
                        Thi[rl * 72 + j * 16 + l15]       = h1;
                        Tlo[rl * 72 + j * 16 + l15]       = f2bf(o1 - bf2f(h1));
                        Thi[rl * 72 + (j + 2) * 16 + l15] = h2;
                        Tlo[rl * 72 + (j + 2) * 16 + l15] = f2bf(o2 - bf2f(h2));
                    }
                }
            }
            #pragma unroll
            for (int p = 0; p < 4; ++p) {    // 32 rows x 128B, full lines
                const int slot = p * 64 + lane;
                const int rr = slot >> 3, c8 = (slot & 7) * 8;
                const size_t ga = (((size_t)(b * NHEAD + hh) * S_LEN) + sb0 + half * 32 + rr) * HDIM + c8;
                *(uint4*)&dh[ga] = *(const uint4*)&Thi[rr * 72 + c8];
                *(uint4*)&dl[ga] = *(const uint4*)&Tlo[rr * 72 + c8];
            }
        }
    } else {
        // V: stage transposed (d-major) and store directly to V^T [bh][d][s]
        u16* const Thi = chunk;              // [64][40]
        u16* const Tlo = chunk + 2560;
        #pragma unroll
        for (int half = 0; half < 2; ++half) {
            #pragma unroll
            for (int i2 = 0; i2 < 2; ++i2) {
                const int i = half * 2 + i2;
                #pragma unroll
                for (int e = 0; e < 4; ++e) {
                    const int rl = i2 * 16 + l16 * 4 + e;     // s within half-tile
                    #pragma unroll
                    for (int j = 0; j < 4; ++j) {
                        const float o = acc[i][j][e];
                        const u16 hb = f2bf(o);
                        Thi[(j * 16 + l15) * 40 + rl] = hb;
                        Tlo[(j * 16 + l15) * 40 + rl] = f2bf(o - bf2f(hb));
                    }
                }
            }
            #pragma unroll
            for (int p = 0; p < 4; ++p) {    // 64 d-rows x 64B
                const int slot = p * 64 + lane;
                const int dd = slot >> 2, s8 = (slot & 3) * 8;
                const size_t ga = (((size_t)(b * NHEAD + hh) * HDIM) + dd) * S_LEN + sb0 + half * 32 + s8;
                *(uint4*)&vthi[ga] = *(const uint4*)&Thi[dd * 40 + s8];
                *(uint4*)&vtlo[ga] = *(const uint4*)&Tlo[dd * 40 + s8];
            }
        }
    }
}

// ---------------- 3. causal flash attention (hi/lo MFMA) ----------------
// grid (qt=32, bh=32), 256 thr = 4 waves, wave w owns q-rows [qt*64+16w, +16).
// qt dispatched longest-first (qt = 31 - blockIdx.x) for causal load balance.
// LDS 54272 B flat: KH|KL|VH|VL (u16 [64][72] each) | PW (float [4][16][68]).
__global__ __launch_bounds__(256)
void attn_mfma(const u16* __restrict__ qhi, const u16* __restrict__ qlo,
               const u16* __restrict__ khi, const u16* __restrict__ klo,
               const u16* __restrict__ vthi, const u16* __restrict__ vtlo,
               u16* __restrict__ ohi, u16* __restrict__ olo)
{
    __shared__ __align__(16) u16 AS[27136];
    u16* const KH = AS;              // 4608 u16
    u16* const KL = AS + 4608;
    u16* const VH = AS + 9216;
    u16* const VL = AS + 13824;
    float* const PW = (float*)(AS + 18432);   // [4][16][68]
    const int tid = threadIdx.x, lane = tid & 63, w = tid >> 6;
    const int l15 = lane & 15, l16 = lane >> 4;
    const int qt = 31 - blockIdx.x;           // longest blocks first
    const int bh = blockIdx.y;
    const size_t sbase = (size_t)bh * S_LEN * HDIM;   // [bh][s][d]
    const size_t dbase = (size_t)bh * HDIM * S_LEN;   // [bh][d][s]
    float* const pw = PW + w * 1088;

    // Q fragments hoisted for the whole kernel (q pre-scaled by 1/8)
    bf16x8 q_h[2], q_l[2];
    {
        const int s = qt * 64 + w * 16 + l15;
        #pragma unroll
        for (int ks = 0; ks < 2; ++ks) {
            const size_t ga = sbase + (size_t)s * HDIM + ks * 32 + l16 * 8;
            q_h[ks] = *(const bf16x8*)&qhi[ga];
            q_l[ks] = *(const bf16x8*)&qlo[ga];
        }
    }

    f32x4 oacc[4];
    #pragma unroll
    for (int t = 0; t < 4; ++t) oacc[t] = (f32x4){0.f, 0.f, 0.f, 0.f};
    float m_i[4], l_i[4];
    #pragma unroll
    for (int e = 0; e < 4; ++e) { m_i[e] = -INFINITY; l_i[e] = 0.f; }

    for (int kt = 0; kt <= qt; ++kt) {
        __syncthreads();                       // protect LDS K/V reuse
        #pragma unroll
        for (int p = 0; p < 2; ++p) {          // reg-stage K and V^T tiles
            const int c = tid + p * 256;       // 512 16B-chunks per tensor
            const int r = c >> 3, dc = (c & 7) * 8;
            const size_t gk = sbase + (size_t)(kt * 64 + r) * HDIM + dc;
            *(uint4*)&KH[r * 72 + dc] = *(const uint4*)&khi[gk];
            *(uint4*)&KL[r * 72 + dc] = *(const uint4*)&klo[gk];
            const size_t gv = dbase + (size_t)r * S_LEN + kt * 64 + dc;
            *(uint4*)&VH[r * 72 + dc] = *(const uint4*)&vthi[gv];
            *(uint4*)&VL[r * 72 + dc] = *(const uint4*)&vtlo[gv];
        }
        __syncthreads();

        // QK^T: scores[16 q-rows][64 k-cols] per wave
        f32x4 st[4];
        #pragma unroll
        for (int t = 0; t < 4; ++t) st[t] = (f32x4){0.f, 0.f, 0.f, 0.f};
        #pragma unroll
        for (int t = 0; t < 4; ++t)
            #pragma unroll
            for (int ks = 0; ks < 2; ++ks) {
                const bf16x8 kf_h = *(const bf16x8*)&KH[(t * 16 + l15) * 72 + ks * 32 + l16 * 8];
                const bf16x8 kf_l = *(const bf16x8*)&KL[(t * 16 + l15) * 72 + ks * 32 + l16 * 8];
                st[t] = mfma16(q_h[ks], kf_h, st[t]);
                st[t] = mfma16(q_h[ks], kf_l, st[t]);
                st[t] = mfma16(q_l[ks], kf_h, st[t]);
            }
        if (kt == qt) {                        // causal mask inside diagonal tile
            #pragma unroll
            for (int t = 0; t < 4; ++t)
                #pragma unroll
                for (int e = 0; e < 4; ++e)
                    if (t * 16 + l15 > w * 16 + l16 * 4 + e) st[t][e] = -1e30f;
        }
        // online softmax (rows live in D-layout: row = 4*l16+e, 16 lanes share a row)
        #pragma unroll
        for (int e = 0; e < 4; ++e) {
            float mx = fmaxf(fmaxf(st[0][e], st[1][e]), fmaxf(st[2][e], st[3][e]));
            #pragma unroll
            for (int msk = 8; msk >= 1; msk >>= 1) mx = fmaxf(mx, __shfl_xor(mx, msk));
            const float mn = fmaxf(m_i[e], mx);
            const float scl = __expf(m_i[e] - mn);
            float rs = 0.f;
            #pragma unroll
            for (int t = 0; t < 4; ++t) {
                const float p = __expf(st[t][e] - mn);
                st[t][e] = p; rs += p;
            }
            #pragma unroll
            for (int msk = 8; msk >= 1; msk >>= 1) rs += __shfl_xor(rs, msk);
            l_i[e] = l_i[e] * scl + rs;
            m_i[e] = mn;
            #pragma unroll
            for (int t = 0; t < 4; ++t) oacc[t][e] *= scl;
        }
        // P: D-layout regs -> wave-private LDS -> A-operand layout + hi/lo split
        #pragma unroll
        for (int t = 0; t < 4; ++t)
            #pragma unroll
            for (int e = 0; e < 4; ++e)
                pw[(l16 * 4 + e) * 68 + t * 16 + l15] = st[t][e];
        bf16x8 p_h[2], p_l[2];
        #pragma unroll
        for (int ks = 0; ks < 2; ++ks) {
            float pf[8];
            *(f32x4*)&pf[0] = *(const f32x4*)&pw[l15 * 68 + ks * 32 + l16 * 8];
            *(f32x4*)&pf[4] = *(const f32x4*)&pw[l15 * 68 + ks * 32 + l16 * 8 + 4];
            #pragma unroll
            for (int u = 0; u < 8; ++u) {
                const u16 hb = f2bf(pf[u]);
                p_h[ks][u] = (short)hb;
                p_l[ks][u] = (short)f2bf(pf[u] - bf2f(hb));
            }
        }
        // PV: out[m][d] += P[m][n] V[n][d]  (V^T tile, n contiguous)
        #pragma unroll
        for (int t = 0; t < 4; ++t)
            #pragma unroll
            for (int ks = 0; ks < 2; ++ks) {
                const bf16x8 vf_h = *(const bf16x8*)&VH[(t * 16 + l15) * 72 + ks * 32 + l16 * 8];
                const bf16x8 vf_l = *(const bf16x8*)&VL[(t * 16 + l15) * 72 + ks * 32 + l16 * 8];
                oacc[t] = mfma16(p_h[ks], vf_h, oacc[t]);
                oacc[t] = mfma16(p_h[ks], vf_l, oacc[t]);
                oacc[t] = mfma16(p_l[ks], vf_h, oacc[t]);
            }
    }
    // ---- epilogue: normalize, split hi/lo, LDS-staged coalesced store ----
    __syncthreads();                          // K/V LDS dead; alias staging over it
    u16* const Ohi = AS + w * 2304;           // [16][72] per wave
    u16* const Olo = Ohi + 1152;
    #pragma unroll
    for (int e = 0; e < 4; ++e) {
        const float invl = 1.f / l_i[e];
        const int rl = l16 * 4 + e;
        #pragma unroll
        for (int t = 0; t < 4; ++t) {
            const float o = oacc[t][e] * invl;
            const u16 hb = f2bf(o);
            Ohi[rl * 72 + t * 16 + l15] = hb;
            Olo[rl * 72 + t * 16 + l15] = f2bf(o - bf2f(hb));
        }
    }
    #pragma unroll
    for (int p = 0; p < 2; ++p) {             // 16 rows x 128B, full lines
        const int slot = p * 64 + lane;
        const int rr = slot >> 3, c8 = (slot & 7) * 8;
        const size_t ga = sbase + (size_t)(qt * 64 + w * 16 + rr) * HDIM + c8;
        *(uint4*)&ohi[ga] = *(const uint4*)&Ohi[rr * 72 + c8];
        *(uint4*)&olo[ga] = *(const uint4*)&Olo[rr * 72 + c8];
    }
}

// ---------------- 4. output projection: out = attn_out @ Wo^T (fp32 out) ----------------
// Reg-staged LDS fill, same 2-phase prefetch as qkv. A gathered from [bh][s][d].
__global__ __launch_bounds__(256)
void proj_mfma(const u16* __restrict__ ahi, const u16* __restrict__ alo,
               const u16* __restrict__ wohi, const u16* __restrict__ wolo,
               float* __restrict__ out)
{
    __shared__ __align__(16) u16 SMEM[16384];   // Ah|Al|Bh|Bl @ 0/4096/8192/12288 u16
    const int tid = threadIdx.x, lane = tid & 63, w = tid >> 6;
    const int l15 = lane & 15, l16 = lane >> 4;
    const int m0 = blockIdx.x * 128, n0 = blockIdx.y * 128;

    const int r0 = tid >> 2, r1 = r0 + 64;
    const int c0 = (tid & 3) * 8;
    // A-row geometry is k-independent
    const int ri0 = m0 + r0, ri1 = m0 + r1;
    const int ab0 = ri0 >> 11, as0 = ri0 & 2047;
    const int ab1 = ri1 >> 11, as1 = ri1 & 2047;

    f32x4 acc[4][4];
    #pragma unroll
    for (int i = 0; i < 4; ++i)
        #pragma unroll
        for (int j = 0; j < 4; ++j) acc[i][j] = (f32x4){0.f, 0.f, 0.f, 0.f};

    uint4 Ah0, Ah1, Al0, Al1, Bh0, Bh1, Bl0, Bl1;
    {
        const int kc = c0;                    // k0 = 0
        const int hh = kc >> 6, dd = kc & 63;
        const size_t a0 = ((size_t)(ab0 * NHEAD + hh) * S_LEN + as0) * HDIM + dd;
        const size_t a1 = ((size_t)(ab1 * NHEAD + hh) * S_LEN + as1) * HDIM + dd;
        const size_t b0 = (size_t)(n0 + r0) * 1024 + c0;
        const size_t b1 = (size_t)(n0 + r1) * 1024 + c0;
        Ah0 = *(const uint4*)&ahi[a0];  Ah1 = *(const uint4*)&ahi[a1];
        Al0 = *(const uint4*)&alo[a0];  Al1 = *(const uint4*)&alo[a1];
        Bh0 = *(const uint4*)&wohi[b0]; Bh1 = *(const uint4*)&wohi[b1];
        Bl0 = *(const uint4*)&wolo[b0]; Bl1 = *(const uint4*)&wolo[b1];
    }

    for (int k0 = 0; k0 < 1024; k0 += 32) {
        __syncthreads();
        *(uint4*)&SMEM[        r0 * 32 + c0] = Ah0;
        *(uint4*)&SMEM[        r1 * 32 + c0] = Ah1;
        *(uint4*)&SMEM[ 4096 + r0 * 32 + c0] = Al0;
        *(uint4*)&SMEM[ 4096 + r1 * 32 + c0] = Al1;
        *(uint4*)&SMEM[ 8192 + r0 * 32 + c0] = Bh0;
        *(uint4*)&SMEM[ 8192 + r1 * 32 + c0] = Bh1;
        *(uint4*)&SMEM[12288 + r0 * 32 + c0] = Bl0;
        *(uint4*)&SMEM[12288 + r1 * 32 + c0] = Bl1;
        __syncthreads();
        if (k0 + 32 < 1024) {
            const int kc = k0 + 32 + c0;
            const int hh = kc >> 6, dd = kc & 63;
            const size_t a0 = ((size_t)(ab0 * NHEAD + hh) * S_LEN + as0) * HDIM + dd;
            const size_t a1 = ((size_t)(ab1 * NHEAD + hh) * S_LEN + as1) * HDIM + dd;
            const size_t b0 = (size_t)(n0 + r0) * 1024 + k0 + 32 + c0;
            const size_t b1 = (size_t)(n0 + r1) * 1024 + k0 + 32 + c0;
            Ah0 = *(const uint4*)&ahi[a0];  Ah1 = *(const uint4*)&ahi[a1];
            Al0 = *(const uint4*)&alo[a0];  Al1 = *(const uint4*)&alo[a1];
            Bh0 = *(const uint4*)&wohi[b0]; Bh1 = *(const uint4*)&wohi[b1];
            Bl0 = *(const uint4*)&wolo[b0]; Bl1 = *(const uint4*)&wolo[b1];
        }
        const int mo = (w >> 1) * 64, no = (w & 1) * 64;
        bf16x8 a_h[4], a_l[4], b_h[4], b_l[4];
        #pragma unroll
        for (int f = 0; f < 4; ++f) {
            const int ao = (mo + f * 16 + l15) * 32 + l16 * 8;
            a_h[f] = *(const bf16x8*)&SMEM[ao];
            a_l[f] = *(const bf16x8*)&SMEM[4096 + ao];
            const int bo = (no + f * 16 + l15) * 32 + l16 * 8;
            b_h[f] = *(const bf16x8*)&SMEM[8192 + bo];
            b_l[f] = *(const bf16x8*)&SMEM[12288 + bo];
        }
        #pragma unroll
        for (int i = 0; i < 4; ++i)
            #pragma unroll
            for (int j = 0; j < 4; ++j) {
                acc[i][j] = mfma16(a_h[i], b_h[j], acc[i][j]);
                acc[i][j] = mfma16(a_h[i], b_l[j], acc[i][j]);
                acc[i][j] = mfma16(a_l[i], b_h[j], acc[i][j]);
            }
    }
    const int mo = (w >> 1) * 64, no = (w & 1) * 64;
    #pragma unroll
    for (int i = 0; i < 4; ++i)
        #pragma unroll
        for (int e = 0; e < 4; ++e) {
            const int row = m0 + mo + i * 16 + l16 * 4 + e;
            #pragma unroll
            for (int j = 0; j < 4; ++j)
                out[(size_t)row * 1024 + n0 + no + j * 16 + l15] = acc[i][j][e];
        }
}

extern "C" void kernel_launch(void* const* d_in, const int* in_sizes, int n_in,
                              void* d_out, int out_size, void* d_ws, size_t ws_size,
                              hipStream_t stream)
{
    const float* x  = (const float*)d_in[0];
    const float* Wq = (const float*)d_in[1];
    const float* Wk = (const float*)d_in[2];
    const float* Wv = (const float*)d_in[3];
    const float* Wo = (const float*)d_in[4];
    float* out = (float*)d_out;

    char* ws = (char*)d_ws;
    const size_t MB = (size_t)1 << 20;
    u16* xhi  = (u16*)(ws +  0 * MB);   // 8 MB, reused as attn-out hi
    u16* xlo  = (u16*)(ws +  8 * MB);   // 8 MB, reused as attn-out lo
    u16* whi  = (u16*)(ws + 16 * MB);   // 8 MB: [4][1024][1024] q,k,v,o
    u16* wlo  = (u16*)(ws + 24 * MB);   // 8 MB
    u16* qhi  = (u16*)(ws + 32 * MB);
    u16* qlo  = (u16*)(ws + 40 * MB);
    u16* khi  = (u16*)(ws + 48 * MB);
    u16* klo  = (u16*)(ws + 56 * MB);
    u16* vthi = (u16*)(ws + 64 * MB);   // [bh][d][s]
    u16* vtlo = (u16*)(ws + 72 * MB);   // total 80 MB

    split_convert<<<8192, 256, 0, stream>>>(x, Wq, Wk, Wv, Wo, xhi, xlo, whi, wlo);
    qkv_mfma<<<dim3(32, 24), 256, 0, stream>>>(xhi, xlo, whi, wlo,
                                               qhi, qlo, khi, klo, vthi, vtlo);
    attn_mfma<<<dim3(32, NBH), 256, 0, stream>>>(qhi, qlo, khi, klo, vthi, vtlo,
                                                 xhi, xlo);
    proj_mfma<<<dim3(32, 8), 256, 0, stream>>>(xhi, xlo,
                                               whi + ((size_t)3 << 20), wlo + ((size_t)3 << 20),
                                               out);
}

// Round 9
// 538.826 us; speedup vs baseline: 1.1135x; 1.0558x over previous
//
#include <hip/hip_runtime.h>
#include <math.h>
#include <stdint.h>

// AttentionMC on MI355X: x(2,2048,1024) fp32; Wq/Wk/Wv/Wo(1024,1024) fp32.
// Split-bf16 (hi/lo, 3-term) MFMA implementation: absmax 9.77e-4 (passed R3/R5/R6).
// R8: R6 falsified staging-mechanics theories (WRITE_SIZE invariant, cold 1.2%-occ
// dispatch = warm dur => chip-global limiter). New theory: XCD L2 locality.
// Default round-robin gives every XCD a ~64MB working set vs 4MB L2 -> ~786MB
// (qkv) + ~530MB (attn) + ~380MB (proj) of fabric traffic. Fix: bijective
// block remaps so each XCD owns an n-stripe (qkv) / head-stripe (attn) /
// m-stripe (proj). Everything else byte-identical to R6.
// Pipeline: split_convert -> qkv_mfma(+RoPE, +V^T) -> attn_mfma -> proj_mfma.
// ws (80 MB): xhi xlo | whi wlo | qhi qlo khi klo | vthi vtlo
//   (xhi/xlo reused as attn-out hi/lo after qkv consumes x).

#define S_LEN 2048
#define NHEAD 16
#define HDIM  64
#define NBH   32

typedef __attribute__((ext_vector_type(8))) short  bf16x8;
typedef __attribute__((ext_vector_type(4))) float  f32x4;
typedef unsigned short u16;
typedef unsigned int   u32;

__device__ __forceinline__ u16 f2bf(float f) {          // RNE fp32->bf16 bits
    u32 u = __float_as_uint(f);
    return (u16)((u + 0x7FFFu + ((u >> 16) & 1u)) >> 16);
}
__device__ __forceinline__ float bf2f(u16 s) {
    return __uint_as_float(((u32)s) << 16);
}
__device__ __forceinline__ f32x4 mfma16(bf16x8 a, bf16x8 b, f32x4 c) {
    return __builtin_amdgcn_mfma_f32_16x16x32_bf16(a, b, c, 0, 0, 0);
}

// ---------------- 1. fp32 -> bf16 hi/lo split for x and all weights ----------------
__global__ __launch_bounds__(256)
void split_convert(const float* __restrict__ x,
                   const float* __restrict__ Wq, const float* __restrict__ Wk,
                   const float* __restrict__ Wv, const float* __restrict__ Wo,
                   u16* __restrict__ xhi, u16* __restrict__ xlo,
                   u16* __restrict__ whi, u16* __restrict__ wlo)
{
    const int g = blockIdx.x * 256 + threadIdx.x;   // float4 index, 2M total
    const float* src; u16 *dhi, *dlo; int loc;
    if (g < 1048576) { src = x; dhi = xhi; dlo = xlo; loc = g; }
    else {
        const int r = g - 1048576;
        const int wsel = r >> 18;                   // 256K float4 per weight
        loc = r & 262143;
        src = (wsel == 0) ? Wq : (wsel == 1) ? Wk : (wsel == 2) ? Wv : Wo;
        dhi = whi + ((size_t)wsel << 20);
        dlo = wlo + ((size_t)wsel << 20);
    }
    const float4 v = reinterpret_cast<const float4*>(src)[loc];
    ushort4 hv, lv;
    hv.x = f2bf(v.x); lv.x = f2bf(v.x - bf2f(hv.x));
    hv.y = f2bf(v.y); lv.y = f2bf(v.y - bf2f(hv.y));
    hv.z = f2bf(v.z); lv.z = f2bf(v.z - bf2f(hv.z));
    hv.w = f2bf(v.w); lv.w = f2bf(v.w - bf2f(hv.w));
    reinterpret_cast<ushort4*>(dhi)[loc] = hv;
    reinterpret_cast<ushort4*>(dlo)[loc] = lv;
}

// ---------------- 2. QKV projection GEMM (hi/lo MFMA) + RoPE + V^T epilogue ----------------
// M=4096, Nglobal=3072 (q|k|v), K=1024. 128x128 tile, BK=32, 4 waves (64x64 each).
// XCD swizzle: lin%8 = XCD; XCD k owns n-blocks {3k,3k+1,3k+2}; within an XCD the
// 3 users of one A-slab are consecutive (A-hot). W-stripe (1.5MB) stays L2-resident.
__global__ __launch_bounds__(256)
void qkv_mfma(const u16* __restrict__ xhi, const u16* __restrict__ xlo,
              const u16* __restrict__ whi, const u16* __restrict__ wlo,
              u16* __restrict__ qhi, u16* __restrict__ qlo,
              u16* __restrict__ khi, u16* __restrict__ klo,
              u16* __restrict__ vthi, u16* __restrict__ vtlo)
{
    __shared__ __align__(16) u16 SMEM[20480];   // 40960 B: Ah|Al|Bh|Bl @ 0/4096/8192/12288 u16
    const int tid = threadIdx.x, lane = tid & 63, w = tid >> 6;
    const int l15 = lane & 15, l16 = lane >> 4;
    // --- XCD-aware bijective remap (768 = 8 XCD x 96) ---
    const int lin = blockIdx.y * 32 + blockIdx.x;
    const int xcd = lin & 7, idx = lin >> 3;     // idx 0..95
    const int nb = xcd * 3 + (idx % 3);          // n-block 0..23 (XCD-striped)
    const int mb = idx / 3;                      // m-block 0..31 (A-slab hot per trio)
    const int m0 = mb * 128;
    const int ng = nb * 128;
    const int tsel = ng >> 10;               // 0=q 1=k 2=v
    const int nloc0 = ng & 1023;
    const u16* __restrict__ Wh = whi + ((size_t)tsel << 20);
    const u16* __restrict__ Wl = wlo + ((size_t)tsel << 20);

    // staging geometry: slot s -> row = s>>2 (0..127), col c0 = (s&3)*8 u16
    const int r0 = tid >> 2, r1 = r0 + 64;
    const int c0 = (tid & 3) * 8;

    f32x4 acc[4][4];
    #pragma unroll
    for (int i = 0; i < 4; ++i)
        #pragma unroll
        for (int j = 0; j < 4; ++j) acc[i][j] = (f32x4){0.f, 0.f, 0.f, 0.f};

    // prologue: load k-tile 0 into regs
    uint4 Ah0, Ah1, Al0, Al1, Bh0, Bh1, Bl0, Bl1;
    {
        const size_t a0 = (size_t)(m0 + r0) * 1024 + c0;
        const size_t a1 = (size_t)(m0 + r1) * 1024 + c0;
        const size_t b0 = (size_t)(nloc0 + r0) * 1024 + c0;
        const size_t b1 = (size_t)(nloc0 + r1) * 1024 + c0;
        Ah0 = *(const uint4*)&xhi[a0]; Ah1 = *(const uint4*)&xhi[a1];
        Al0 = *(const uint4*)&xlo[a0]; Al1 = *(const uint4*)&xlo[a1];
        Bh0 = *(const uint4*)&Wh[b0];  Bh1 = *(const uint4*)&Wh[b1];
        Bl0 = *(const uint4*)&Wl[b0];  Bl1 = *(const uint4*)&Wl[b1];
    }

    for (int k0 = 0; k0 < 1024; k0 += 32) {
        __syncthreads();                          // prev tile's frag reads done
        *(uint4*)&SMEM[        r0 * 32 + c0] = Ah0;
        *(uint4*)&SMEM[        r1 * 32 + c0] = Ah1;
        *(uint4*)&SMEM[ 4096 + r0 * 32 + c0] = Al0;
        *(uint4*)&SMEM[ 4096 + r1 * 32 + c0] = Al1;
        *(uint4*)&SMEM[ 8192 + r0 * 32 + c0] = Bh0;
        *(uint4*)&SMEM[ 8192 + r1 * 32 + c0] = Bh1;
        *(uint4*)&SMEM[12288 + r0 * 32 + c0] = Bl0;
        *(uint4*)&SMEM[12288 + r1 * 32 + c0] = Bl1;
        __syncthreads();                          // tile visible to all waves
        if (k0 + 32 < 1024) {                     // prefetch next tile under MFMA
            const int kn = k0 + 32;
            const size_t a0 = (size_t)(m0 + r0) * 1024 + kn + c0;
            const size_t a1 = (size_t)(m0 + r1) * 1024 + kn + c0;
            const size_t b0 = (size_t)(nloc0 + r0) * 1024 + kn + c0;
            const size_t b1 = (size_t)(nloc0 + r1) * 1024 + kn + c0;
            Ah0 = *(const uint4*)&xhi[a0]; Ah1 = *(const uint4*)&xhi[a1];
            Al0 = *(const uint4*)&xlo[a0]; Al1 = *(const uint4*)&xlo[a1];
            Bh0 = *(const uint4*)&Wh[b0];  Bh1 = *(const uint4*)&Wh[b1];
            Bl0 = *(const uint4*)&Wl[b0];  Bl1 = *(const uint4*)&Wl[b1];
        }
        const int mo = (w >> 1) * 64, no = (w & 1) * 64;
        bf16x8 a_h[4], a_l[4], b_h[4], b_l[4];
        #pragma unroll
        for (int f = 0; f < 4; ++f) {
            const int ao = (mo + f * 16 + l15) * 32 + l16 * 8;
            a_h[f] = *(const bf16x8*)&SMEM[ao];
            a_l[f] = *(const bf16x8*)&SMEM[4096 + ao];
            const int bo = (no + f * 16 + l15) * 32 + l16 * 8;
            b_h[f] = *(const bf16x8*)&SMEM[8192 + bo];
            b_l[f] = *(const bf16x8*)&SMEM[12288 + bo];
        }
        #pragma unroll
        for (int i = 0; i < 4; ++i)
            #pragma unroll
            for (int j = 0; j < 4; ++j) {
                acc[i][j] = mfma16(a_h[i], b_h[j], acc[i][j]);
                acc[i][j] = mfma16(a_h[i], b_l[j], acc[i][j]);
                acc[i][j] = mfma16(a_l[i], b_h[j], acc[i][j]);
            }
    }

    // ---- epilogue: LDS-staged, fully-coalesced uint4 stores ----
    __syncthreads();                         // all waves done reading SMEM
    const int mo = (w >> 1) * 64, no = (w & 1) * 64;
    const int hh = (nloc0 + no) >> 6;        // head (wave's 64-col block is head-aligned)
    const int mrow = m0 + mo;
    const int b = mrow >> 11, sb0 = mrow & 2047;
    u16* const chunk = SMEM + w * 5120;      // 10240 B per wave

    if (tsel < 2) {
        u16* __restrict__ dh = tsel ? khi : qhi;
        u16* __restrict__ dl = tsel ? klo : qlo;
        const float scl = tsel ? 1.0f : 0.125f;   // fold 1/sqrt(hd) into q
        // inv_freq: <=1 ulp of 10000^(-d/32); only 2 distinct d per thread
        const float inv0 = (float)exp((double)l15        * -0.28782313662425574);
        const float inv1 = (float)exp((double)(l15 + 16) * -0.28782313662425574);
        u16* const Thi = chunk;              // [32][72]
        u16* const Tlo = chunk + 2304;
        #pragma unroll
        for (int half = 0; half < 2; ++half) {
            #pragma unroll
            for (int i2 = 0; i2 < 2; ++i2) {
                const int i = half * 2 + i2;
                #pragma unroll
                for (int e = 0; e < 4; ++e) {
                    const int rl = i2 * 16 + l16 * 4 + e;     // row within half-tile
                    const int s = sb0 + half * 32 + rl;
                    #pragma unroll
                    for (int j = 0; j < 2; ++j) {             // pair (d, d+32) = frags (j, j+2)
                        const float inv = j ? inv1 : inv0;
                        const float ang = (float)s * inv;
                        const float sn = sinf(ang), cs = cosf(ang);
                        const float x1 = acc[i][j][e], x2 = acc[i][j + 2][e];
                        const float o1 = (x1 * cs - x2 * sn) * scl;
                        const float o2 = (x1 * sn + x2 * cs) * scl;
                        const u16 h1 = f2bf(o1), h2 = f2bf(o2);
                        Thi[rl * 72 + j * 16 + l15]       = h1;
                        Tlo[rl * 72 + j * 16 + l15]       = f2bf(o1 - bf2f(h1));
                        Thi[rl * 72 + (j + 2) * 16 + l15] = h2;
                        Tlo[rl * 72 + (j + 2) * 16 + l15] = f2bf(o2 - bf2f(h2));
                    }
                }
            }
            #pragma unroll
            for (int p = 0; p < 4; ++p) {    // 32 rows x 128B, full lines
                const int slot = p * 64 + lane;
                const int rr = slot >> 3, c8 = (slot & 7) * 8;
                const size_t ga = (((size_t)(b * NHEAD + hh) * S_LEN) + sb0 + half * 32 + rr) * HDIM + c8;
                *(uint4*)&dh[ga] = *(const uint4*)&Thi[rr * 72 + c8];
                *(uint4*)&dl[ga] = *(const uint4*)&Tlo[rr * 72 + c8];
            }
        }
    } else {
        // V: stage transposed (d-major) and store directly to V^T [bh][d][s]
        u16* const Thi = chunk;              // [64][40]
        u16* const Tlo = chunk + 2560;
        #pragma unroll
        for (int half = 0; half < 2; ++half) {
            #pragma unroll
            for (int i2 = 0; i2 < 2; ++i2) {
                const int i = half * 2 + i2;
                #pragma unroll
                for (int e = 0; e < 4; ++e) {
                    const int rl = i2 * 16 + l16 * 4 + e;     // s within half-tile
                    #pragma unroll
                    for (int j = 0; j < 4; ++j) {
                        const float o = acc[i][j][e];
                        const u16 hb = f2bf(o);
                        Thi[(j * 16 + l15) * 40 + rl] = hb;
                        Tlo[(j * 16 + l15) * 40 + rl] = f2bf(o - bf2f(hb));
                    }
                }
            }
            #pragma unroll
            for (int p = 0; p < 4; ++p) {    // 64 d-rows x 64B
                const int slot = p * 64 + lane;
                const int dd = slot >> 2, s8 = (slot & 3) * 8;
                const size_t ga = (((size_t)(b * NHEAD + hh) * HDIM) + dd) * S_LEN + sb0 + half * 32 + s8;
                *(uint4*)&vthi[ga] = *(const uint4*)&Thi[dd * 40 + s8];
                *(uint4*)&vtlo[ga] = *(const uint4*)&Tlo[dd * 40 + s8];
            }
        }
    }
}

// ---------------- 3. causal flash attention (hi/lo MFMA) ----------------
// grid (32,32), 256 thr = 4 waves, wave w owns q-rows [qt*64+16w, +16).
// XCD swizzle: XCD k owns heads {4k..4k+3} (KV 4MB = L2-resident);
// within head, qt longest-first.
// LDS 54272 B flat: KH|KL|VH|VL (u16 [64][72] each) | PW (float [4][16][68]).
__global__ __launch_bounds__(256)
void attn_mfma(const u16* __restrict__ qhi, const u16* __restrict__ qlo,
               const u16* __restrict__ khi, const u16* __restrict__ klo,
               const u16* __restrict__ vthi, const u16* __restrict__ vtlo,
               u16* __restrict__ ohi, u16* __restrict__ olo)
{
    __shared__ __align__(16) u16 AS[27136];
    u16* const KH = AS;              // 4608 u16
    u16* const KL = AS + 4608;
    u16* const VH = AS + 9216;
    u16* const VL = AS + 13824;
    float* const PW = (float*)(AS + 18432);   // [4][16][68]
    const int tid = threadIdx.x, lane = tid & 63, w = tid >> 6;
    const int l15 = lane & 15, l16 = lane >> 4;
    // --- XCD-aware bijective remap (1024 = 8 XCD x 128) ---
    const int lin = blockIdx.y * 32 + blockIdx.x;
    const int xcd = lin & 7, idx = lin >> 3;      // idx 0..127
    const int bh = xcd * 4 + (idx >> 5);          // head 0..31 (XCD-striped)
    const int qt = 31 - (idx & 31);               // longest blocks first
    const size_t sbase = (size_t)bh * S_LEN * HDIM;   // [bh][s][d]
    const size_t dbase = (size_t)bh * HDIM * S_LEN;   // [bh][d][s]
    float* const pw = PW + w * 1088;

    // Q fragments hoisted for the whole kernel (q pre-scaled by 1/8)
    bf16x8 q_h[2], q_l[2];
    {
        const int s = qt * 64 + w * 16 + l15;
        #pragma unroll
        for (int ks = 0; ks < 2; ++ks) {
            const size_t ga = sbase + (size_t)s * HDIM + ks * 32 + l16 * 8;
            q_h[ks] = *(const bf16x8*)&qhi[ga];
            q_l[ks] = *(const bf16x8*)&qlo[ga];
        }
    }

    f32x4 oacc[4];
    #pragma unroll
    for (int t = 0; t < 4; ++t) oacc[t] = (f32x4){0.f, 0.f, 0.f, 0.f};
    float m_i[4], l_i[4];
    #pragma unroll
    for (int e = 0; e < 4; ++e) { m_i[e] = -INFINITY; l_i[e] = 0.f; }

    for (int kt = 0; kt <= qt; ++kt) {
        __syncthreads();                       // protect LDS K/V reuse
        #pragma unroll
        for (int p = 0; p < 2; ++p) {          // reg-stage K and V^T tiles
            const int c = tid + p * 256;       // 512 16B-chunks per tensor
            const int r = c >> 3, dc = (c & 7) * 8;
            const size_t gk = sbase + (size_t)(kt * 64 + r) * HDIM + dc;
            *(uint4*)&KH[r * 72 + dc] = *(const uint4*)&khi[gk];
            *(uint4*)&KL[r * 72 + dc] = *(const uint4*)&klo[gk];
            const size_t gv = dbase + (size_t)r * S_LEN + kt * 64 + dc;
            *(uint4*)&VH[r * 72 + dc] = *(const uint4*)&vthi[gv];
            *(uint4*)&VL[r * 72 + dc] = *(const uint4*)&vtlo[gv];
        }
        __syncthreads();

        // QK^T: scores[16 q-rows][64 k-cols] per wave
        f32x4 st[4];
        #pragma unroll
        for (int t = 0; t < 4; ++t) st[t] = (f32x4){0.f, 0.f, 0.f, 0.f};
        #pragma unroll
        for (int t = 0; t < 4; ++t)
            #pragma unroll
            for (int ks = 0; ks < 2; ++ks) {
                const bf16x8 kf_h = *(const bf16x8*)&KH[(t * 16 + l15) * 72 + ks * 32 + l16 * 8];
                const bf16x8 kf_l = *(const bf16x8*)&KL[(t * 16 + l15) * 72 + ks * 32 + l16 * 8];
                st[t] = mfma16(q_h[ks], kf_h, st[t]);
                st[t] = mfma16(q_h[ks], kf_l, st[t]);
                st[t] = mfma16(q_l[ks], kf_h, st[t]);
            }
        if (kt == qt) {                        // causal mask inside diagonal tile
            #pragma unroll
            for (int t = 0; t < 4; ++t)
                #pragma unroll
                for (int e = 0; e < 4; ++e)
                    if (t * 16 + l15 > w * 16 + l16 * 4 + e) st[t][e] = -1e30f;
        }
        // online softmax (rows live in D-layout: row = 4*l16+e, 16 lanes share a row)
        #pragma unroll
        for (int e = 0; e < 4; ++e) {
            float mx = fmaxf(fmaxf(st[0][e], st[1][e]), fmaxf(st[2][e], st[3][e]));
            #pragma unroll
            for (int msk = 8; msk >= 1; msk >>= 1) mx = fmaxf(mx, __shfl_xor(mx, msk));
            const float mn = fmaxf(m_i[e], mx);
            const float scl = __expf(m_i[e] - mn);
            float rs = 0.f;
            #pragma unroll
            for (int t = 0; t < 4; ++t) {
                const float p = __expf(st[t][e] - mn);
                st[t][e] = p; rs += p;
            }
            #pragma unroll
            for (int msk = 8; msk >= 1; msk >>= 1) rs += __shfl_xor(rs, msk);
            l_i[e] = l_i[e] * scl + rs;
            m_i[e] = mn;
            #pragma unroll
            for (int t = 0; t < 4; ++t) oacc[t][e] *= scl;
        }
        // P: D-layout regs -> wave-private LDS -> A-operand layout + hi/lo split
        #pragma unroll
        for (int t = 0; t < 4; ++t)
            #pragma unroll
            for (int e = 0; e < 4; ++e)
                pw[(l16 * 4 + e) * 68 + t * 16 + l15] = st[t][e];
        bf16x8 p_h[2], p_l[2];
        #pragma unroll
        for (int ks = 0; ks < 2; ++ks) {
            float pf[8];
            *(f32x4*)&pf[0] = *(const f32x4*)&pw[l15 * 68 + ks * 32 + l16 * 8];
            *(f32x4*)&pf[4] = *(const f32x4*)&pw[l15 * 68 + ks * 32 + l16 * 8 + 4];
            #pragma unroll
            for (int u = 0; u < 8; ++u) {
                const u16 hb = f2bf(pf[u]);
                p_h[ks][u] = (short)hb;
                p_l[ks][u] = (short)f2bf(pf[u] - bf2f(hb));
            }
        }
        // PV: out[m][d] += P[m][n] V[n][d]  (V^T tile, n contiguous)
        #pragma unroll
        for (int t = 0; t < 4; ++t)
            #pragma unroll
            for (int ks = 0; ks < 2; ++ks) {
                const bf16x8 vf_h = *(const bf16x8*)&VH[(t * 16 + l15) * 72 + ks * 32 + l16 * 8];
                const bf16x8 vf_l = *(const bf16x8*)&VL[(t * 16 + l15) * 72 + ks * 32 + l16 * 8];
                oacc[t] = mfma16(p_h[ks], vf_h, oacc[t]);
                oacc[t] = mfma16(p_h[ks], vf_l, oacc[t]);
                oacc[t] = mfma16(p_l[ks], vf_h, oacc[t]);
            }
    }
    // ---- epilogue: normalize, split hi/lo, LDS-staged coalesced store ----
    __syncthreads();                          // K/V LDS dead; alias staging over it
    u16* const Ohi = AS + w * 2304;           // [16][72] per wave
    u16* const Olo = Ohi + 1152;
    #pragma unroll
    for (int e = 0; e < 4; ++e) {
        const float invl = 1.f / l_i[e];
        const int rl = l16 * 4 + e;
        #pragma unroll
        for (int t = 0; t < 4; ++t) {
            const float o = oacc[t][e] * invl;
            const u16 hb = f2bf(o);
            Ohi[rl * 72 + t * 16 + l15] = hb;
            Olo[rl * 72 + t * 16 + l15] = f2bf(o - bf2f(hb));
        }
    }
    #pragma unroll
    for (int p = 0; p < 2; ++p) {             // 16 rows x 128B, full lines
        const int slot = p * 64 + lane;
        const int rr = slot >> 3, c8 = (slot & 7) * 8;
        const size_t ga = sbase + (size_t)(qt * 64 + w * 16 + rr) * HDIM + c8;
        *(uint4*)&ohi[ga] = *(const uint4*)&Ohi[rr * 72 + c8];
        *(uint4*)&olo[ga] = *(const uint4*)&Olo[rr * 72 + c8];
    }
}

// ---------------- 4. output projection: out = attn_out @ Wo^T (fp32 out) ----------------
// Reg-staged LDS fill, 2-phase prefetch. XCD swizzle: XCD k owns m-blocks
// {4k..4k+3}; within XCD consecutive blocks share the A-slab (A-hot).
__global__ __launch_bounds__(256)
void proj_mfma(const u16* __restrict__ ahi, const u16* __restrict__ alo,
               const u16* __restrict__ wohi, const u16* __restrict__ wolo,
               float* __restrict__ out)
{
    __shared__ __align__(16) u16 SMEM[16384];   // Ah|Al|Bh|Bl @ 0/4096/8192/12288 u16
    const int tid = threadIdx.x, lane = tid & 63, w = tid >> 6;
    const int l15 = lane & 15, l16 = lane >> 4;
    // --- XCD-aware bijective remap (256 = 8 XCD x 32) ---
    const int lin = blockIdx.y * 32 + blockIdx.x;
    const int xcd = lin & 7, idx = lin >> 3;     // idx 0..31
    const int mb = xcd * 4 + (idx >> 3);         // m-block 0..31 (XCD-striped)
    const int nb = idx & 7;                      // n-block 0..7 (A-slab hot)
    const int m0 = mb * 128, n0 = nb * 128;

    const int r0 = tid >> 2, r1 = r0 + 64;
    const int c0 = (tid & 3) * 8;
    // A-row geometry is k-independent
    const int ri0 = m0 + r0, ri1 = m0 + r1;
    const int ab0 = ri0 >> 11, as0 = ri0 & 2047;
    const int ab1 = ri1 >> 11, as1 = ri1 & 2047;

    f32x4 acc[4][4];
    #pragma unroll
    for (int i = 0; i < 4; ++i)
        #pragma unroll
        for (int j = 0; j < 4; ++j) acc[i][j] = (f32x4){0.f, 0.f, 0.f, 0.f};

    uint4 Ah0, Ah1, Al0, Al1, Bh0, Bh1, Bl0, Bl1;
    {
        const int kc = c0;                    // k0 = 0
        const int hh = kc >> 6, dd = kc & 63;
        const size_t a0 = ((size_t)(ab0 * NHEAD + hh) * S_LEN + as0) * HDIM + dd;
        const size_t a1 = ((size_t)(ab1 * NHEAD + hh) * S_LEN + as1) * HDIM + dd;
        const size_t b0 = (size_t)(n0 + r0) * 1024 + c0;
        const size_t b1 = (size_t)(n0 + r1) * 1024 + c0;
        Ah0 = *(const uint4*)&ahi[a0];  Ah1 = *(const uint4*)&ahi[a1];
        Al0 = *(const uint4*)&alo[a0];  Al1 = *(const uint4*)&alo[a1];
        Bh0 = *(const uint4*)&wohi[b0]; Bh1 = *(const uint4*)&wohi[b1];
        Bl0 = *(const uint4*)&wolo[b0]; Bl1 = *(const uint4*)&wolo[b1];
    }

    for (int k0 = 0; k0 < 1024; k0 += 32) {
        __syncthreads();
        *(uint4*)&SMEM[        r0 * 32 + c0] = Ah0;
        *(uint4*)&SMEM[        r1 * 32 + c0] = Ah1;
        *(uint4*)&SMEM[ 4096 + r0 * 32 + c0] = Al0;
        *(uint4*)&SMEM[ 4096 + r1 * 32 + c0] = Al1;
        *(uint4*)&SMEM[ 8192 + r0 * 32 + c0] = Bh0;
        *(uint4*)&SMEM[ 8192 + r1 * 32 + c0] = Bh1;
        *(uint4*)&SMEM[12288 + r0 * 32 + c0] = Bl0;
        *(uint4*)&SMEM[12288 + r1 * 32 + c0] = Bl1;
        __syncthreads();
        if (k0 + 32 < 1024) {
            const int kc = k0 + 32 + c0;
            const int hh = kc >> 6, dd = kc & 63;
            const size_t a0 = ((size_t)(ab0 * NHEAD + hh) * S_LEN + as0) * HDIM + dd;
            const size_t a1 = ((size_t)(ab1 * NHEAD + hh) * S_LEN + as1) * HDIM + dd;
            const size_t b0 = (size_t)(n0 + r0) * 1024 + k0 + 32 + c0;
            const size_t b1 = (size_t)(n0 + r1) * 1024 + k0 + 32 + c0;
            Ah0 = *(const uint4*)&ahi[a0];  Ah1 = *(const uint4*)&ahi[a1];
            Al0 = *(const uint4*)&alo[a0];  Al1 = *(const uint4*)&alo[a1];
            Bh0 = *(const uint4*)&wohi[b0]; Bh1 = *(const uint4*)&wohi[b1];
            Bl0 = *(const uint4*)&wolo[b0]; Bl1 = *(const uint4*)&wolo[b1];
        }
        const int mo = (w >> 1) * 64, no = (w & 1) * 64;
        bf16x8 a_h[4], a_l[4], b_h[4], b_l[4];
        #pragma unroll
        for (int f = 0; f < 4; ++f) {
            const int ao = (mo + f * 16 + l15) * 32 + l16 * 8;
            a_h[f] = *(const bf16x8*)&SMEM[ao];
            a_l[f] = *(const bf16x8*)&SMEM[4096 + ao];
            const int bo = (no + f * 16 + l15) * 32 + l16 * 8;
            b_h[f] = *(const bf16x8*)&SMEM[8192 + bo];
            b_l[f] = *(const bf16x8*)&SMEM[12288 + bo];
        }
        #pragma unroll
        for (int i = 0; i < 4; ++i)
            #pragma unroll
            for (int j = 0; j < 4; ++j) {
                acc[i][j] = mfma16(a_h[i], b_h[j], acc[i][j]);
                acc[i][j] = mfma16(a_h[i], b_l[j], acc[i][j]);
                acc[i][j] = mfma16(a_l[i], b_h[j], acc[i][j]);
            }
    }
    const int mo = (w >> 1) * 64, no = (w & 1) * 64;
    #pragma unroll
    for (int i = 0; i < 4; ++i)
        #pragma unroll
        for (int e = 0; e < 4; ++e) {
            const int row = m0 + mo + i * 16 + l16 * 4 + e;
            #pragma unroll
            for (int j = 0; j < 4; ++j)
                out[(size_t)row * 1024 + n0 + no + j * 16 + l15] = acc[i][j][e];
        }
}

extern "C" void kernel_launch(void* const* d_in, const int* in_sizes, int n_in,
                              void* d_out, int out_size, void* d_ws, size_t ws_size,
                              hipStream_t stream)
{
    const float* x  = (const float*)d_in[0];
    const float* Wq = (const float*)d_in[1];
    const float* Wk = (const float*)d_in[2];
    const float* Wv = (const float*)d_in[3];
    const float* Wo = (const float*)d_in[4];
    float* out = (float*)d_out;

    char* ws = (char*)d_ws;
    const size_t MB = (size_t)1 << 20;
    u16* xhi  = (u16*)(ws +  0 * MB);   // 8 MB, reused as attn-out hi
    u16* xlo  = (u16*)(ws +  8 * MB);   // 8 MB, reused as attn-out lo
    u16* whi  = (u16*)(ws + 16 * MB);   // 8 MB: [4][1024][1024] q,k,v,o
    u16* wlo  = (u16*)(ws + 24 * MB);   // 8 MB
    u16* qhi  = (u16*)(ws + 32 * MB);
    u16* qlo  = (u16*)(ws + 40 * MB);
    u16* khi  = (u16*)(ws + 48 * MB);
    u16* klo  = (u16*)(ws + 56 * MB);
    u16* vthi = (u16*)(ws + 64 * MB);   // [bh][d][s]
    u16* vtlo = (u16*)(ws + 72 * MB);   // total 80 MB

    split_convert<<<8192, 256, 0, stream>>>(x, Wq, Wk, Wv, Wo, xhi, xlo, whi, wlo);
    qkv_mfma<<<dim3(32, 24), 256, 0, stream>>>(xhi, xlo, whi, wlo,
                                               qhi, qlo, khi, klo, vthi, vtlo);
    attn_mfma<<<dim3(32, NBH), 256, 0, stream>>>(qhi, qlo, khi, klo, vthi, vtlo,
                                                 xhi, xlo);
    proj_mfma<<<dim3(32, 8), 256, 0, stream>>>(xhi, xlo,
                                               whi + ((size_t)3 << 20), wlo + ((size_t)3 << 20),
                                               out);
}